// Round 7
// baseline (299.682 us; speedup 1.0000x reference)
//
#include <hip/hip_runtime.h>

typedef unsigned short u16;
typedef __attribute__((ext_vector_type(4))) unsigned short u16x4;
typedef __attribute__((ext_vector_type(2))) unsigned u32x2;
typedef __attribute__((ext_vector_type(8))) __bf16 bf16x8;
typedef __attribute__((ext_vector_type(2))) __bf16 bf16x2;
typedef __attribute__((ext_vector_type(4))) float f32x4;

#define DEV __device__ __forceinline__

DEV u16 f2b(float f) {
    union { float f; unsigned u; } v; v.f = f;
    unsigned r = v.u + 0x7FFFu + ((v.u >> 16) & 1u);
    return (u16)(r >> 16);
}
DEV unsigned pk2(float a, float b) {   // two f32 -> packed bf16x2 (RNE, hw cvt)
    bf16x2 t; t.x = (__bf16)a; t.y = (__bf16)b;
    union { bf16x2 v; unsigned u; } c; c.v = t; return c.u;
}
DEV u16 cvt1(float f) {
    __bf16 h = (__bf16)f;
    union { __bf16 h; u16 u; } c; c.h = h; return c.u;
}

// async global->LDS, 16B per lane; lds dest = wave-uniform base + lane*16
DEV void gl_lds16(const u16* g, const u16* l) {
    __builtin_amdgcn_global_load_lds(
        (__attribute__((address_space(1))) void*)(unsigned long long)g,
        (__attribute__((address_space(3))) void*)(unsigned long long)l,
        16, 0, 0);
}

// counted-vmcnt phase sync (T4): never drain to 0 in the main loop.
DEV void sync_keep4() {
    asm volatile("s_waitcnt vmcnt(4)" ::: "memory");
    __builtin_amdgcn_s_barrier();
    asm volatile("" ::: "memory");
}
DEV void sync_keep6() {
    asm volatile("s_waitcnt vmcnt(6)" ::: "memory");
    __builtin_amdgcn_s_barrier();
    asm volatile("" ::: "memory");
}
DEV void sync_keep8() {
    asm volatile("s_waitcnt vmcnt(8)" ::: "memory");
    __builtin_amdgcn_s_barrier();
    asm volatile("" ::: "memory");
}
DEV void sync_drain() {
    asm volatile("s_waitcnt vmcnt(0)" ::: "memory");
    __builtin_amdgcn_s_barrier();
    asm volatile("" ::: "memory");
}

// fused prep: blocks [0,8192) convert x fp32->bf16; [8192,9216) transpose W0..3
__global__ __launch_bounds__(256) void k_prep(const float* __restrict__ xf, u16* __restrict__ xb,
                                              const float* w0, const float* w1,
                                              const float* w2, const float* w3,
                                              u16* __restrict__ dst)
{
    __shared__ u16 t[64][68];
    int bx = blockIdx.x;
    if (bx < 8192) {
        size_t base = (size_t)bx * 1024 + threadIdx.x * 4;
        float4 v = *(const float4*)&xf[base];
        u16x4 o; o.x = f2b(v.x); o.y = f2b(v.y); o.z = f2b(v.z); o.w = f2b(v.w);
        *(u16x4*)&xb[base] = o;
        return;
    }
    bx -= 8192;
    int z = bx >> 8, tile = bx & 255;
    const float* src = z == 0 ? w0 : z == 1 ? w1 : z == 2 ? w2 : w3;
    u16* d = dst + (size_t)z * 1048576;
    int tx = threadIdx.x & 15, ty = threadIdx.x >> 4;
    int c0 = (tile & 15) * 64, r0 = (tile >> 4) * 64;
#pragma unroll
    for (int i = 0; i < 4; i++) {
        int r = ty + i * 16;
        float4 v = *(const float4*)&src[(size_t)(r0 + r) * 1024 + c0 + tx * 4];
        t[r][tx * 4 + 0] = f2b(v.x); t[r][tx * 4 + 1] = f2b(v.y);
        t[r][tx * 4 + 2] = f2b(v.z); t[r][tx * 4 + 3] = f2b(v.w);
    }
    __syncthreads();
#pragma unroll
    for (int i = 0; i < 4; i++) {
        int cl = ty + i * 16;
        u16x4 v;
        v.x = t[tx * 4 + 0][cl];
        v.y = t[tx * 4 + 1][cl];
        v.z = t[tx * 4 + 2][cl];
        v.w = t[tx * 4 + 3][cl];
        *(u16x4*)&d[(size_t)(c0 + cl) * 1024 + r0 + tx * 4] = v;
    }
}

// ---------------------------------------------------------------------------
// Fused QKV GEMM v3: B (weights) read DIRECTLY from global/L2 into registers
// (software-pipelined one phase ahead); only A (x) staged through LDS.
// r6 post-mortem: LDS pipe (10 ds_read + 5 gl_lds-write per wave-phase) was
// ~640cy/block-phase vs MFMA ~470cy and the barrier serialized them -> all
// structures plateaued 65-70us. W is 6MB bf16, L2-resident, per-lane frag is
// 16 contiguous bytes of WT[n][k] (64B-coalesced per quad-group) -> no LDS
// needed. LDS traffic drops ~4x; 32KB/block; VGPR ~190 (2 waves/SIMD).
// vmcnt invariant (mixed gl_lds + global_load stream, verified per phase):
//   prologue: LOADB(0,0); stage A(0,kh0)+A(0,kh1); vmcnt(0); barrier.
//   phase(t,kh): ds_read A[t][kh]; stage A(t+1,kh); vmcnt(8); barrier;
//                MFMA(a, b_cur); LOADB(next phase) -> b_nxt.
//   At phase(t,kh)'s sync, newest 8 in flight = 2 stage(t+1,kh) + 6 b(t,kh);
//   vmcnt(8) forces stage(t,kh^1) [= next phase's ds_read data]. b regs are
//   waited by the compiler before MFMA use (issued 1 phase earlier, covered).
//   Tail: tile15 ph0 vmcnt(6) forces stage(15,1); ph1 plain (compiler waits).
// Grid (16,64) = 1024 blocks, 2 blocks/CU resident.
// ---------------------------------------------------------------------------
__global__ __launch_bounds__(256, 2) void k_qkvf(const u16* __restrict__ x, const u16* __restrict__ WT,
                                                 const float* __restrict__ bq, const float* __restrict__ bk,
                                                 const float* __restrict__ bv,
                                                 u16* __restrict__ QK, u16* __restrict__ Vt)
{
    __shared__ u16 lds[16384];
    const int tid = threadIdx.x;
    const int w = tid >> 6, lane = tid & 63, quad = lane >> 4, l16 = lane & 15;
    const int wr = w >> 1, wc = w & 1;              // 2M x 2N wave grid
    const int m0 = blockIdx.y * 128, n0 = blockIdx.x * 64;
    const int K = 1024;

    f32x4 acc[3][4][2] = {};                        // [matrix][mi][ni]

    // A staging source swizzle (proven pair-row XOR; 2 rounds of 256 thr)
    int srowA[2], skofA[2];
#pragma unroll
    for (int ph = 0; ph < 2; ph++) {
        int L = (ph * 256 + tid) * 8;
        int pr = L >> 6, cp = (L >> 3) & 7;
        int c = cp ^ (pr & 7);
        srowA[ph] = pr * 2 + (c >> 2); skofA[ph] = (c & 3) * 8;
    }
    const u16* Ap0 = x + ((size_t)m0 + srowA[0]) * K + skofA[0];
    const u16* Ap1 = x + ((size_t)m0 + srowA[1]) * K + skofA[1];
    const int wof = w * 512;

    // LDS map (u16): A sub(p,kh) at p*8192 + kh*4096; 16384 u16 = 32 KB
    auto STAGE_A = [&](int pb, int t, int kh) {
        size_t ko = (size_t)t * 64 + kh * 32;
        int la = pb * 8192 + kh * 4096 + wof;
        gl_lds16(Ap0 + ko, lds + la);
        gl_lds16(Ap1 + ko, lds + la + 2048);
    };

    int aoff[4];
#pragma unroll
    for (int mi = 0; mi < 4; mi++) {
        int row = wr * 64 + mi * 16 + l16;
        aoff[mi] = (row >> 1) * 64 + (((((row & 1) << 2) | quad) ^ ((row >> 1) & 7)) << 3);
    }

    // B direct-from-L2 per-lane pointers: frag(m,ni) at phase koff is the 16B
    // WT[m][n0 + wc*32 + ni*16 + l16][koff + quad*8 .. +7] (matches the MFMA
    // B-operand layout the proven LDS path delivered).
    const u16* bbase[3][2];
#pragma unroll
    for (int m = 0; m < 3; m++)
#pragma unroll
        for (int ni = 0; ni < 2; ni++)
            bbase[m][ni] = WT + (size_t)m * 1048576
                         + (size_t)(n0 + wc * 32 + ni * 16 + l16) * 1024 + quad * 8;

    auto LOADA = [&](int pb, int kh, bf16x8 (&a)[4]) {
        const u16* Ab = lds + pb * 8192 + kh * 4096;
#pragma unroll
        for (int mi = 0; mi < 4; mi++) a[mi] = *(const bf16x8*)&Ab[aoff[mi]];
    };
    auto LOADB = [&](int koff, bf16x8 (&b)[3][2]) {
#pragma unroll
        for (int m = 0; m < 3; m++)
#pragma unroll
            for (int ni = 0; ni < 2; ni++)
                b[m][ni] = *(const bf16x8*)(bbase[m][ni] + koff);
    };
    auto MM = [&](const bf16x8 (&a)[4], const bf16x8 (&b)[3][2]) {
        __builtin_amdgcn_s_setprio(1);
#pragma unroll
        for (int m = 0; m < 3; m++)
#pragma unroll
            for (int mi = 0; mi < 4; mi++)
#pragma unroll
                for (int ni = 0; ni < 2; ni++)
                    acc[m][mi][ni] = __builtin_amdgcn_mfma_f32_16x16x32_bf16(a[mi], b[m][ni], acc[m][mi][ni], 0, 0, 0);
        __builtin_amdgcn_s_setprio(0);
    };

    bf16x8 b0[3][2], b1[3][2];

    // prologue: b(0,kh0) + full tile-0 A stage; one-time full drain
    LOADB(0, b0);
    STAGE_A(0, 0, 0);
    STAGE_A(0, 0, 1);
    sync_drain();

    const int NT = 16;
    for (int t = 0; t < NT - 1; ++t) {
        const int p = t & 1, qb = p ^ 1;
        {   // phase kh0: consume b0, prefetch b1 = (t, kh1)
            bf16x8 a[4];
            LOADA(p, 0, a);
            STAGE_A(qb, t + 1, 0);
            sync_keep8();
            MM(a, b0);
            LOADB(t * 64 + 32, b1);
        }
        {   // phase kh1: consume b1, prefetch b0 = (t+1, kh0)
            bf16x8 a[4];
            LOADA(p, 1, a);
            STAGE_A(qb, t + 1, 1);
            sync_keep8();
            MM(a, b1);
            LOADB((t + 1) * 64, b0);
        }
    }
    {   // tile 15 (p = 1): no further staging
        bf16x8 a[4];
        LOADA(1, 0, a);
        sync_keep6();               // forces stage(15,kh1) for the next read
        MM(a, b0);
        LOADB(15 * 64 + 32, b1);
        LOADA(1, 1, a);
        MM(a, b1);                  // compiler waits b1
    }

    float bsq[2], bsk[2], bsv2[2];
#pragma unroll
    for (int ni = 0; ni < 2; ni++) {
        int col = n0 + wc * 32 + ni * 16 + l16;
        bsq[ni] = bq[col]; bsk[ni] = bk[col]; bsv2[ni] = bv[col];
    }

    // Q (scaled) and K: row-dense bf16
#pragma unroll
    for (int mi = 0; mi < 4; mi++) {
        int row = m0 + wr * 64 + mi * 16 + quad * 4;
#pragma unroll
        for (int ni = 0; ni < 2; ni++) {
            int col = n0 + wc * 32 + ni * 16 + l16;
#pragma unroll
            for (int r2 = 0; r2 < 4; r2++) {
                QK[(size_t)(row + r2) * 1024 + col] =
                    f2b((acc[0][mi][ni][r2] + bsq[ni]) * 0.18033688011f);
                QK[(size_t)8388608 + (size_t)(row + r2) * 1024 + col] =
                    f2b(acc[1][mi][ni][r2] + bsk[ni]);
            }
        }
    }
    // V: transpose-scatter into Vt [b*16+h][d=64][n=1024]
    {
        int bb = m0 >> 10, nbase = (m0 & 1023) + wr * 64;
#pragma unroll
        for (int mi = 0; mi < 4; mi++) {
            int nrow = nbase + mi * 16 + quad * 4;
#pragma unroll
            for (int ni = 0; ni < 2; ni++) {
                int col = n0 + wc * 32 + ni * 16 + l16;
                int hh = col >> 6, dd = col & 63;
                u16x4 pk;
                pk.x = f2b(acc[2][mi][ni][0] + bsv2[ni]);
                pk.y = f2b(acc[2][mi][ni][1] + bsv2[ni]);
                pk.z = f2b(acc[2][mi][ni][2] + bsv2[ni]);
                pk.w = f2b(acc[2][mi][ni][3] + bsv2[ni]);
                *(u16x4*)&Vt[(size_t)(bb * 16 + hh) * 65536 + (size_t)dd * 1024 + nrow] = pk;
            }
        }
    }
}

// ---------------------------------------------------------------------------
// output projection v2 (fp32 out, unchanged from r6): 4-wave blocks, BM=128
// BN=128, ring-4 counted-vmcnt(4), LDS 64 KB -> 2 blocks/CU. Grid (8,64).
// ---------------------------------------------------------------------------
__global__ __launch_bounds__(256, 2) void k_out4(const u16* __restrict__ A, const u16* __restrict__ WoT,
                                                 const float* __restrict__ bo, float* __restrict__ C)
{
    __shared__ u16 lds[32768];
    const int tid = threadIdx.x;
    const int w = tid >> 6, lane = tid & 63, quad = lane >> 4, l16 = lane & 15;
    const int wr = w >> 1, wc = w & 1;
    const int m0 = blockIdx.y * 128, n0 = blockIdx.x * 128;
    const int K = 1024;

    f32x4 acc[4][4] = {};

    int srowA[2], skofA[2];
#pragma unroll
    for (int ph = 0; ph < 2; ph++) {
        int L = (ph * 256 + tid) * 8;
        int pr = L >> 6, cp = (L >> 3) & 7;
        int c = cp ^ (pr & 7);
        srowA[ph] = pr * 2 + (c >> 2); skofA[ph] = (c & 3) * 8;
    }
    const u16* Ap0 = A + ((size_t)m0 + srowA[0]) * K + skofA[0];
    const u16* Ap1 = A + ((size_t)m0 + srowA[1]) * K + skofA[1];
    const u16* Bq0 = WoT + ((size_t)n0 + srowA[0]) * K + skofA[0];
    const u16* Bq1 = WoT + ((size_t)n0 + srowA[1]) * K + skofA[1];
    const int wof = w * 512;

    auto STAGE = [&](int pb, int t, int kh) {
        size_t ko = (size_t)t * 64 + kh * 32;
        int la = pb * 8192 + kh * 4096 + wof;
        gl_lds16(Ap0 + ko, lds + la);
        gl_lds16(Ap1 + ko, lds + la + 2048);
        gl_lds16(Bq0 + ko, lds + 16384 + la);
        gl_lds16(Bq1 + ko, lds + 16384 + la + 2048);
    };

    int aoff[4], boff[4];
#pragma unroll
    for (int mi = 0; mi < 4; mi++) {
        int row = wr * 64 + mi * 16 + l16;
        aoff[mi] = (row >> 1) * 64 + (((((row & 1) << 2) | quad) ^ ((row >> 1) & 7)) << 3);
    }
#pragma unroll
    for (int ni = 0; ni < 4; ni++) {
        int r = wc * 64 + ni * 16 + l16;
        boff[ni] = (r >> 1) * 64 + (((((r & 1) << 2) | quad) ^ ((r >> 1) & 7)) << 3);
    }

    auto LOADF = [&](int pb, int kh, bf16x8 (&a)[4], bf16x8 (&b)[4]) {
        const u16* Ab = lds + pb * 8192 + kh * 4096;
        const u16* Bb = lds + 16384 + pb * 8192 + kh * 4096;
#pragma unroll
        for (int mi = 0; mi < 4; mi++) a[mi] = *(const bf16x8*)&Ab[aoff[mi]];
#pragma unroll
        for (int ni = 0; ni < 4; ni++) b[ni] = *(const bf16x8*)&Bb[boff[ni]];
    };

    auto MM = [&](const bf16x8 (&a)[4], const bf16x8 (&b)[4]) {
        __builtin_amdgcn_s_setprio(1);
#pragma unroll
        for (int mi = 0; mi < 4; mi++)
#pragma unroll
            for (int ni = 0; ni < 4; ni++)
                acc[mi][ni] = __builtin_amdgcn_mfma_f32_16x16x32_bf16(a[mi], b[ni], acc[mi][ni], 0, 0, 0);
        __builtin_amdgcn_s_setprio(0);
    };

    STAGE(0, 0, 0);
    STAGE(0, 0, 1);
    sync_keep4();

    const int NT = 16;
    for (int t = 0; t < NT - 1; ++t) {
        const int p = t & 1, qb = p ^ 1;
        bf16x8 a[4], b[4];
        LOADF(p, 0, a, b);
        STAGE(qb, t + 1, 0);
        sync_keep4();
        MM(a, b);
        LOADF(p, 1, a, b);
        STAGE(qb, t + 1, 1);
        sync_keep4();
        MM(a, b);
    }
    {
        const int p = (NT - 1) & 1;
        bf16x8 a[4], b[4];
        LOADF(p, 0, a, b);
        sync_drain();
        MM(a, b);
        LOADF(p, 1, a, b);
        MM(a, b);
    }

    float bs[4];
#pragma unroll
    for (int ni = 0; ni < 4; ni++)
        bs[ni] = bo[n0 + wc * 64 + ni * 16 + l16];
#pragma unroll
    for (int mi = 0; mi < 4; mi++) {
        int row = m0 + wr * 64 + mi * 16 + quad * 4;
#pragma unroll
        for (int ni = 0; ni < 4; ni++) {
            int col = n0 + wc * 64 + ni * 16 + l16;
#pragma unroll
            for (int r2 = 0; r2 < 4; r2++)
                C[(size_t)(row + r2) * 1024 + col] = acc[mi][ni][r2] + bs[ni];
        }
    }
}

// ---------------------------------------------------------------------------
// attention v5 (proven): 32-key K/V tiles, 26 KB LDS, 4 blocks/CU
// all-resident, wave-private q rows, dbuf K/V, 1 barrier/kt, XOR-swizzled
// staging, ones-MFMA row-sum, coalesced O store. grid (8,128)
// ---------------------------------------------------------------------------
__global__ __launch_bounds__(256, 4) void k_attn(const u16* __restrict__ Q, const u16* __restrict__ K,
                                                 const u16* __restrict__ Vt, u16* __restrict__ O)
{
    __shared__ u16 lds[13312];
    const int tid = threadIdx.x, w = tid >> 6, lane = tid & 63, quad = lane >> 4, l16 = lane & 15;
    const int bh = blockIdx.y, b = bh >> 4, h = bh & 15;
    const int q0 = blockIdx.x * 128;
    const u16* Qp = Q + ((size_t)b * 1024 + q0) * 1024 + h * 64;
    const u16* Kp = K + (size_t)b * 1048576 + h * 64;
    const u16* Vp = Vt + (size_t)bh * 65536;
    u16* Op = O + ((size_t)b * 1024 + q0) * 1024 + h * 64;
    u16* Pw = lds + 8192 + w * 1280;   // 32 rows x 40 u16, wave-private

    // stage Q [128][64] swizzled into [0,8192)
#pragma unroll
    for (int i = 0; i < 4; i++) {
        int g = (w * 4 + i) * 64 + lane;
        int row = g >> 3, c = (g & 7) ^ (row & 7);
        gl_lds16(Qp + (size_t)row * 1024 + c * 8, lds + (w * 4 + i) * 512);
    }
    __syncthreads();
    bf16x8 qa[2][2];
#pragma unroll
    for (int ni = 0; ni < 2; ni++)
#pragma unroll
        for (int d2 = 0; d2 < 2; d2++)
            qa[ni][d2] = *(const bf16x8*)&lds[(w * 32 + ni * 16 + l16) * 64 + ((d2 * 4 + quad) ^ (l16 & 7)) * 8];
    __syncthreads();   // all waves done reading Q before KV staging overwrites it

    // stage kt0 into buf0
    {
        int g = w * 64 + lane;
        int row = g >> 3, c = (g & 7) ^ (row & 7);
        gl_lds16(Kp + (size_t)row * 1024 + c * 8, lds + w * 512);
        int rv = g >> 2, cv = (g & 3) ^ (rv & 3);
        gl_lds16(Vp + (size_t)rv * 1024 + cv * 8, lds + 2048 + w * 512);
    }
    __syncthreads();

    bf16x8 ones;
#pragma unroll
    for (int j = 0; j < 8; j++) ones[j] = (__bf16)1.0f;

    f32x4 acc_o[2][4] = {};   // [ni][di]: D[q][d], col=d(l16), row=q-part
    f32x4 acc_l[2] = {};      // [ni]: l(q), row-aligned with acc_o

    for (int kt = 0; kt < 32; kt++) {
        const u16* buf = lds + (kt & 1) * 4096;
        if (kt < 31) {
            int k0n = (kt + 1) * 32;
            u16* dst = lds + ((kt + 1) & 1) * 4096;
            int g = w * 64 + lane;
            int row = g >> 3, c = (g & 7) ^ (row & 7);
            gl_lds16(Kp + (size_t)(k0n + row) * 1024 + c * 8, dst + w * 512);
            int rv = g >> 2, cv = (g & 3) ^ (rv & 3);
            gl_lds16(Vp + (size_t)rv * 1024 + k0n + cv * 8, dst + 2048 + w * 512);
        }

        // S^T: D[k=mi*16+quad*4+reg][q=w*32+ni*16+l16], accumulate over d halves
        f32x4 s[2][2] = {};
#pragma unroll
        for (int d2 = 0; d2 < 2; d2++) {
            bf16x8 ka[2];
#pragma unroll
            for (int mi = 0; mi < 2; mi++)
                ka[mi] = *(const bf16x8*)&buf[(mi * 16 + l16) * 64 + ((d2 * 4 + quad) ^ (l16 & 7)) * 8];
#pragma unroll
            for (int mi = 0; mi < 2; mi++)
#pragma unroll
                for (int ni = 0; ni < 2; ni++)
                    s[mi][ni] = __builtin_amdgcn_mfma_f32_16x16x32_bf16(ka[mi], qa[ni][d2], s[mi][ni], 0, 0, 0);
        }

        // exp2 (Q pre-scaled), pack 4 consecutive k -> wave-private Ps
#pragma unroll
        for (int ni = 0; ni < 2; ni++)
#pragma unroll
            for (int mi = 0; mi < 2; mi++) {
                float e0 = __builtin_amdgcn_exp2f(s[mi][ni][0]);
                float e1 = __builtin_amdgcn_exp2f(s[mi][ni][1]);
                float e2 = __builtin_amdgcn_exp2f(s[mi][ni][2]);
                float e3 = __builtin_amdgcn_exp2f(s[mi][ni][3]);
                u32x2 pk; pk.x = pk2(e0, e1); pk.y = pk2(e2, e3);
                *(u32x2*)&Pw[(ni * 16 + l16) * 40 + mi * 16 + quad * 4] = pk;
            }

        // O[q][d] += P[q][k32] V[k32][d]; l(q) += P*ones; same-wave LDS RAW
        {
            bf16x8 pa[2], vb[4];
#pragma unroll
            for (int ni = 0; ni < 2; ni++)
                pa[ni] = *(const bf16x8*)&Pw[(ni * 16 + l16) * 40 + quad * 8];
#pragma unroll
            for (int di = 0; di < 4; di++)
                vb[di] = *(const bf16x8*)&buf[2048 + (di * 16 + l16) * 32 + (quad ^ (l16 & 3)) * 8];
#pragma unroll
            for (int ni = 0; ni < 2; ni++) {
                acc_l[ni] = __builtin_amdgcn_mfma_f32_16x16x32_bf16(pa[ni], ones, acc_l[ni], 0, 0, 0);
#pragma unroll
                for (int di = 0; di < 4; di++)
                    acc_o[ni][di] = __builtin_amdgcn_mfma_f32_16x16x32_bf16(pa[ni], vb[di], acc_o[ni][di], 0, 0, 0);
            }
        }
        __syncthreads();
    }

    // normalize + store (coalesced along d = di*16 + l16)
#pragma unroll
    for (int ni = 0; ni < 2; ni++) {
#pragma unroll
        for (int r = 0; r < 4; r++) {
            float inv = __builtin_amdgcn_rcpf(acc_l[ni][r]);
            int row = w * 32 + ni * 16 + quad * 4 + r;
#pragma unroll
            for (int di = 0; di < 4; di++)
                Op[(size_t)row * 1024 + di * 16 + l16] = cvt1(acc_o[ni][di][r] * inv);
        }
    }
}

extern "C" void kernel_launch(void* const* d_in, const int* in_sizes, int n_in,
                              void* d_out, int out_size, void* d_ws, size_t ws_size,
                              hipStream_t stream)
{
    (void)in_sizes; (void)n_in; (void)out_size; (void)ws_size;
    // inputs (fp32): 0:x 4:Wq 5:bq 6:Wk 7:bk 8:Wv 9:bv 10:Wo 11:bo
    // 1,2,3,12..19: conditioning — mathematically cancels in softmax.
    const float* xf  = (const float*)d_in[0];
    const float* Wqf = (const float*)d_in[4];  const float* bqf = (const float*)d_in[5];
    const float* Wkf = (const float*)d_in[6];  const float* bkf = (const float*)d_in[7];
    const float* Wvf = (const float*)d_in[8];  const float* bvf = (const float*)d_in[9];
    const float* Wof = (const float*)d_in[10]; const float* bof = (const float*)d_in[11];

    u16* ws  = (u16*)d_ws;
    u16* Qw  = ws;                              // 8M el bf16 (pre-scaled by log2e/8)
    u16* Kw  = ws + (size_t)8388608;            // 8M el bf16
    u16* Vtw = ws + (size_t)16777216;           // 8M el bf16 [b*16+h][64][1024]
    u16* WT  = ws + (size_t)25165824;           // 4M el bf16 [4][n=1024][k=1024]
    u16* xb  = ws + (size_t)29360128;           // 8M el bf16 x; reused as AO after k_qkv
    u16* AO  = xb;

    k_prep<<<9216, 256, 0, stream>>>(xf, xb, Wqf, Wkf, Wvf, Wof, WT);
    k_qkvf<<<dim3(16, 64), 256, 0, stream>>>(xb, WT, bqf, bkf, bvf, Qw, Vtw);
    k_attn<<<dim3(8, 128), 256, 0, stream>>>(Qw, Kw, Vtw, AO);
    k_out4<<<dim3(8, 64), 256, 0, stream>>>(AO, WT + (size_t)3145728, bof, (float*)d_out);
}

// Round 8
// 271.519 us; speedup vs baseline: 1.1037x; 1.1037x over previous
//
#include <hip/hip_runtime.h>

typedef unsigned short u16;
typedef __attribute__((ext_vector_type(4))) unsigned short u16x4;
typedef __attribute__((ext_vector_type(2))) unsigned u32x2;
typedef __attribute__((ext_vector_type(8))) __bf16 bf16x8;
typedef __attribute__((ext_vector_type(2))) __bf16 bf16x2;
typedef __attribute__((ext_vector_type(4))) float f32x4;

#define DEV __device__ __forceinline__

DEV u16 f2b(float f) {
    union { float f; unsigned u; } v; v.f = f;
    unsigned r = v.u + 0x7FFFu + ((v.u >> 16) & 1u);
    return (u16)(r >> 16);
}
DEV unsigned pk2(float a, float b) {   // two f32 -> packed bf16x2 (RNE, hw cvt)
    bf16x2 t; t.x = (__bf16)a; t.y = (__bf16)b;
    union { bf16x2 v; unsigned u; } c; c.v = t; return c.u;
}
DEV u16 cvt1(float f) {
    __bf16 h = (__bf16)f;
    union { __bf16 h; u16 u; } c; c.h = h; return c.u;
}

// async global->LDS, 16B per lane; lds dest = wave-uniform base + lane*16
DEV void gl_lds16(const u16* g, const u16* l) {
    __builtin_amdgcn_global_load_lds(
        (__attribute__((address_space(1))) void*)(unsigned long long)g,
        (__attribute__((address_space(3))) void*)(unsigned long long)l,
        16, 0, 0);
}

// counted-vmcnt phase sync (T4): never drain to 0 in the main loop.
DEV void sync_keep4() {
    asm volatile("s_waitcnt vmcnt(4)" ::: "memory");
    __builtin_amdgcn_s_barrier();
    asm volatile("" ::: "memory");
}
DEV void sync_drain() {
    asm volatile("s_waitcnt vmcnt(0)" ::: "memory");
    __builtin_amdgcn_s_barrier();
    asm volatile("" ::: "memory");
}

// fused prep: blocks [0,8192) convert x fp32->bf16; [8192,9216) transpose W0..3
__global__ __launch_bounds__(256) void k_prep(const float* __restrict__ xf, u16* __restrict__ xb,
                                              const float* w0, const float* w1,
                                              const float* w2, const float* w3,
                                              u16* __restrict__ dst)
{
    __shared__ u16 t[64][68];
    int bx = blockIdx.x;
    if (bx < 8192) {
        size_t base = (size_t)bx * 1024 + threadIdx.x * 4;
        float4 v = *(const float4*)&xf[base];
        u16x4 o; o.x = f2b(v.x); o.y = f2b(v.y); o.z = f2b(v.z); o.w = f2b(v.w);
        *(u16x4*)&xb[base] = o;
        return;
    }
    bx -= 8192;
    int z = bx >> 8, tile = bx & 255;
    const float* src = z == 0 ? w0 : z == 1 ? w1 : z == 2 ? w2 : w3;
    u16* d = dst + (size_t)z * 1048576;
    int tx = threadIdx.x & 15, ty = threadIdx.x >> 4;
    int c0 = (tile & 15) * 64, r0 = (tile >> 4) * 64;
#pragma unroll
    for (int i = 0; i < 4; i++) {
        int r = ty + i * 16;
        float4 v = *(const float4*)&src[(size_t)(r0 + r) * 1024 + c0 + tx * 4];
        t[r][tx * 4 + 0] = f2b(v.x); t[r][tx * 4 + 1] = f2b(v.y);
        t[r][tx * 4 + 2] = f2b(v.z); t[r][tx * 4 + 3] = f2b(v.w);
    }
    __syncthreads();
#pragma unroll
    for (int i = 0; i < 4; i++) {
        int cl = ty + i * 16;
        u16x4 v;
        v.x = t[tx * 4 + 0][cl];
        v.y = t[tx * 4 + 1][cl];
        v.z = t[tx * 4 + 2][cl];
        v.w = t[tx * 4 + 3][cl];
        *(u16x4*)&d[(size_t)(c0 + cl) * 1024 + r0 + tx * 4] = v;
    }
}

// ---------------------------------------------------------------------------
// gemm4: the r6-proven 4-wave 128x128 bf16 GEMM core (ring-4 sub-buffers,
// counted vmcnt(4), pair-row XOR swizzle, 0 bank conflicts, 64 KB LDS,
// 2 blocks/CU). r7 post-mortem: B-from-L2 regressed 1.8x (compiler-inserted
// vmcnt(2)-equivalent before each MFMA serialized L2 latency) -> B stays in
// LDS. QKV is split into 3 dispatches of this core (vs r6 fused) to surface
// k_attn/k_prep counters in the top-5 table; cost ~+2us HBM (x re-reads).
// MODE 0 bf16 +scale / 1 Vt-scatter / 2 fp32 (all r2-proven epilogues).
// Grid (8,64) = 512 blocks = 2.0 rounds at 2 blocks/CU.
// ---------------------------------------------------------------------------
template <int MODE>
DEV void gemm4(const u16* __restrict__ A, const u16* __restrict__ BT,
               const float* __restrict__ bias,
               u16* __restrict__ Cb, float* __restrict__ Cf,
               int m0, int n0, float oscale, u16* lds)
{
    const int tid = threadIdx.x;
    const int w = tid >> 6, lane = tid & 63, quad = lane >> 4, l16 = lane & 15;
    const int wr = w >> 1, wc = w & 1;
    const int K = 1024;

    f32x4 acc[4][4] = {};

    int srowA[2], skofA[2];
#pragma unroll
    for (int ph = 0; ph < 2; ph++) {
        int L = (ph * 256 + tid) * 8;
        int pr = L >> 6, cp = (L >> 3) & 7;
        int c = cp ^ (pr & 7);
        srowA[ph] = pr * 2 + (c >> 2); skofA[ph] = (c & 3) * 8;
    }
    const u16* Ap0 = A + ((size_t)m0 + srowA[0]) * K + skofA[0];
    const u16* Ap1 = A + ((size_t)m0 + srowA[1]) * K + skofA[1];
    const u16* Bq0 = BT + ((size_t)n0 + srowA[0]) * K + skofA[0];
    const u16* Bq1 = BT + ((size_t)n0 + srowA[1]) * K + skofA[1];
    const int wof = w * 512;

    // LDS map (u16): A sub(p,kh) at p*8192+kh*4096; B at 16384 + same
    auto STAGE = [&](int pb, int t, int kh) {
        size_t ko = (size_t)t * 64 + kh * 32;
        int la = pb * 8192 + kh * 4096 + wof;
        gl_lds16(Ap0 + ko, lds + la);
        gl_lds16(Ap1 + ko, lds + la + 2048);
        gl_lds16(Bq0 + ko, lds + 16384 + la);
        gl_lds16(Bq1 + ko, lds + 16384 + la + 2048);
    };

    int aoff[4], boff[4];
#pragma unroll
    for (int mi = 0; mi < 4; mi++) {
        int row = wr * 64 + mi * 16 + l16;
        aoff[mi] = (row >> 1) * 64 + (((((row & 1) << 2) | quad) ^ ((row >> 1) & 7)) << 3);
    }
#pragma unroll
    for (int ni = 0; ni < 4; ni++) {
        int r = wc * 64 + ni * 16 + l16;
        boff[ni] = (r >> 1) * 64 + (((((r & 1) << 2) | quad) ^ ((r >> 1) & 7)) << 3);
    }

    auto LOADF = [&](int pb, int kh, bf16x8 (&a)[4], bf16x8 (&b)[4]) {
        const u16* Ab = lds + pb * 8192 + kh * 4096;
        const u16* Bb = lds + 16384 + pb * 8192 + kh * 4096;
#pragma unroll
        for (int mi = 0; mi < 4; mi++) a[mi] = *(const bf16x8*)&Ab[aoff[mi]];
#pragma unroll
        for (int ni = 0; ni < 4; ni++) b[ni] = *(const bf16x8*)&Bb[boff[ni]];
    };

    auto MM = [&](const bf16x8 (&a)[4], const bf16x8 (&b)[4]) {
        __builtin_amdgcn_s_setprio(1);
#pragma unroll
        for (int mi = 0; mi < 4; mi++)
#pragma unroll
            for (int ni = 0; ni < 4; ni++)
                acc[mi][ni] = __builtin_amdgcn_mfma_f32_16x16x32_bf16(a[mi], b[ni], acc[mi][ni], 0, 0, 0);
        __builtin_amdgcn_s_setprio(0);
    };

    STAGE(0, 0, 0);
    STAGE(0, 0, 1);
    sync_keep4();

    const int NT = 16;
    for (int t = 0; t < NT - 1; ++t) {
        const int p = t & 1, qb = p ^ 1;
        bf16x8 a[4], b[4];
        LOADF(p, 0, a, b);
        STAGE(qb, t + 1, 0);
        sync_keep4();
        MM(a, b);
        LOADF(p, 1, a, b);
        STAGE(qb, t + 1, 1);
        sync_keep4();
        MM(a, b);
    }
    {
        const int p = (NT - 1) & 1;
        bf16x8 a[4], b[4];
        LOADF(p, 0, a, b);
        sync_drain();
        MM(a, b);
        LOADF(p, 1, a, b);
        MM(a, b);
    }

    float bs[4];
#pragma unroll
    for (int ni = 0; ni < 4; ni++)
        bs[ni] = bias[n0 + wc * 64 + ni * 16 + l16];

    if (MODE == 0) {
#pragma unroll
        for (int mi = 0; mi < 4; mi++) {
            int row = m0 + wr * 64 + mi * 16 + quad * 4;
#pragma unroll
            for (int ni = 0; ni < 4; ni++) {
                int col = n0 + wc * 64 + ni * 16 + l16;
#pragma unroll
                for (int r2 = 0; r2 < 4; r2++)
                    Cb[(size_t)(row + r2) * 1024 + col] = f2b((acc[mi][ni][r2] + bs[ni]) * oscale);
            }
        }
    } else if (MODE == 1) {
        int bb = m0 >> 10;
        int nbase = (m0 & 1023) + wr * 64;
#pragma unroll
        for (int mi = 0; mi < 4; mi++) {
            int nrow = nbase + mi * 16 + quad * 4;
#pragma unroll
            for (int ni = 0; ni < 4; ni++) {
                int col = n0 + wc * 64 + ni * 16 + l16;
                int hh = col >> 6, dd = col & 63;
                u16x4 pk;
                pk.x = f2b(acc[mi][ni][0] + bs[ni]);
                pk.y = f2b(acc[mi][ni][1] + bs[ni]);
                pk.z = f2b(acc[mi][ni][2] + bs[ni]);
                pk.w = f2b(acc[mi][ni][3] + bs[ni]);
                *(u16x4*)&Cb[(size_t)(bb * 16 + hh) * 65536 + (size_t)dd * 1024 + nrow] = pk;
            }
        }
    } else {
#pragma unroll
        for (int mi = 0; mi < 4; mi++) {
            int row = m0 + wr * 64 + mi * 16 + quad * 4;
#pragma unroll
            for (int ni = 0; ni < 4; ni++) {
                int col = n0 + wc * 64 + ni * 16 + l16;
#pragma unroll
                for (int r2 = 0; r2 < 4; r2++)
                    Cf[(size_t)(row + r2) * 1024 + col] = acc[mi][ni][r2] + bs[ni];
            }
        }
    }
}

// Q projection (pre-scaled by log2(e)/8): grid (8,64)
__global__ __launch_bounds__(256, 2) void k_gq(const u16* __restrict__ x, const u16* __restrict__ WT,
                                               const float* __restrict__ bq, u16* __restrict__ Q)
{
    __shared__ u16 lds[32768];
    gemm4<0>(x, WT, bq, Q, (float*)0, blockIdx.y * 128, blockIdx.x * 128, 0.18033688011f, lds);
}
// K projection: grid (8,64)
__global__ __launch_bounds__(256, 2) void k_gk(const u16* __restrict__ x, const u16* __restrict__ WT,
                                               const float* __restrict__ bk, u16* __restrict__ Ko)
{
    __shared__ u16 lds[32768];
    gemm4<0>(x, WT + (size_t)1048576, bk, Ko, (float*)0, blockIdx.y * 128, blockIdx.x * 128, 1.0f, lds);
}
// V projection -> Vt scatter: grid (8,64)
__global__ __launch_bounds__(256, 2) void k_gv(const u16* __restrict__ x, const u16* __restrict__ WT,
                                               const float* __restrict__ bv, u16* __restrict__ Vt)
{
    __shared__ u16 lds[32768];
    gemm4<1>(x, WT + (size_t)2097152, bv, Vt, (float*)0, blockIdx.y * 128, blockIdx.x * 128, 1.0f, lds);
}
// output projection (fp32 out): grid (8,64)
__global__ __launch_bounds__(256, 2) void k_out4(const u16* __restrict__ A, const u16* __restrict__ WoT,
                                                 const float* __restrict__ bo, float* __restrict__ C)
{
    __shared__ u16 lds[32768];
    gemm4<2>(A, WoT, bo, (u16*)0, C, blockIdx.y * 128, blockIdx.x * 128, 1.0f, lds);
}

// ---------------------------------------------------------------------------
// attention v5 (proven): 32-key K/V tiles, 26 KB LDS, 4 blocks/CU
// all-resident, wave-private q rows, dbuf K/V, 1 barrier/kt, XOR-swizzled
// staging, ones-MFMA row-sum, coalesced O store. grid (8,128)
// ---------------------------------------------------------------------------
__global__ __launch_bounds__(256, 4) void k_attn(const u16* __restrict__ Q, const u16* __restrict__ K,
                                                 const u16* __restrict__ Vt, u16* __restrict__ O)
{
    __shared__ u16 lds[13312];
    const int tid = threadIdx.x, w = tid >> 6, lane = tid & 63, quad = lane >> 4, l16 = lane & 15;
    const int bh = blockIdx.y, b = bh >> 4, h = bh & 15;
    const int q0 = blockIdx.x * 128;
    const u16* Qp = Q + ((size_t)b * 1024 + q0) * 1024 + h * 64;
    const u16* Kp = K + (size_t)b * 1048576 + h * 64;
    const u16* Vp = Vt + (size_t)bh * 65536;
    u16* Op = O + ((size_t)b * 1024 + q0) * 1024 + h * 64;
    u16* Pw = lds + 8192 + w * 1280;   // 32 rows x 40 u16, wave-private

    // stage Q [128][64] swizzled into [0,8192)
#pragma unroll
    for (int i = 0; i < 4; i++) {
        int g = (w * 4 + i) * 64 + lane;
        int row = g >> 3, c = (g & 7) ^ (row & 7);
        gl_lds16(Qp + (size_t)row * 1024 + c * 8, lds + (w * 4 + i) * 512);
    }
    __syncthreads();
    bf16x8 qa[2][2];
#pragma unroll
    for (int ni = 0; ni < 2; ni++)
#pragma unroll
        for (int d2 = 0; d2 < 2; d2++)
            qa[ni][d2] = *(const bf16x8*)&lds[(w * 32 + ni * 16 + l16) * 64 + ((d2 * 4 + quad) ^ (l16 & 7)) * 8];
    __syncthreads();   // all waves done reading Q before KV staging overwrites it

    // stage kt0 into buf0
    {
        int g = w * 64 + lane;
        int row = g >> 3, c = (g & 7) ^ (row & 7);
        gl_lds16(Kp + (size_t)row * 1024 + c * 8, lds + w * 512);
        int rv = g >> 2, cv = (g & 3) ^ (rv & 3);
        gl_lds16(Vp + (size_t)rv * 1024 + cv * 8, lds + 2048 + w * 512);
    }
    __syncthreads();

    bf16x8 ones;
#pragma unroll
    for (int j = 0; j < 8; j++) ones[j] = (__bf16)1.0f;

    f32x4 acc_o[2][4] = {};   // [ni][di]: D[q][d], col=d(l16), row=q-part
    f32x4 acc_l[2] = {};      // [ni]: l(q), row-aligned with acc_o

    for (int kt = 0; kt < 32; kt++) {
        const u16* buf = lds + (kt & 1) * 4096;
        if (kt < 31) {
            int k0n = (kt + 1) * 32;
            u16* dst = lds + ((kt + 1) & 1) * 4096;
            int g = w * 64 + lane;
            int row = g >> 3, c = (g & 7) ^ (row & 7);
            gl_lds16(Kp + (size_t)(k0n + row) * 1024 + c * 8, dst + w * 512);
            int rv = g >> 2, cv = (g & 3) ^ (rv & 3);
            gl_lds16(Vp + (size_t)rv * 1024 + k0n + cv * 8, dst + 2048 + w * 512);
        }

        // S^T: D[k=mi*16+quad*4+reg][q=w*32+ni*16+l16], accumulate over d halves
        f32x4 s[2][2] = {};
#pragma unroll
        for (int d2 = 0; d2 < 2; d2++) {
            bf16x8 ka[2];
#pragma unroll
            for (int mi = 0; mi < 2; mi++)
                ka[mi] = *(const bf16x8*)&buf[(mi * 16 + l16) * 64 + ((d2 * 4 + quad) ^ (l16 & 7)) * 8];
#pragma unroll
            for (int mi = 0; mi < 2; mi++)
#pragma unroll
                for (int ni = 0; ni < 2; ni++)
                    s[mi][ni] = __builtin_amdgcn_mfma_f32_16x16x32_bf16(ka[mi], qa[ni][d2], s[mi][ni], 0, 0, 0);
        }

        // exp2 (Q pre-scaled), pack 4 consecutive k -> wave-private Ps
#pragma unroll
        for (int ni = 0; ni < 2; ni++)
#pragma unroll
            for (int mi = 0; mi < 2; mi++) {
                float e0 = __builtin_amdgcn_exp2f(s[mi][ni][0]);
                float e1 = __builtin_amdgcn_exp2f(s[mi][ni][1]);
                float e2 = __builtin_amdgcn_exp2f(s[mi][ni][2]);
                float e3 = __builtin_amdgcn_exp2f(s[mi][ni][3]);
                u32x2 pk; pk.x = pk2(e0, e1); pk.y = pk2(e2, e3);
                *(u32x2*)&Pw[(ni * 16 + l16) * 40 + mi * 16 + quad * 4] = pk;
            }

        // O[q][d] += P[q][k32] V[k32][d]; l(q) += P*ones; same-wave LDS RAW
        {
            bf16x8 pa[2], vb[4];
#pragma unroll
            for (int ni = 0; ni < 2; ni++)
                pa[ni] = *(const bf16x8*)&Pw[(ni * 16 + l16) * 40 + quad * 8];
#pragma unroll
            for (int di = 0; di < 4; di++)
                vb[di] = *(const bf16x8*)&buf[2048 + (di * 16 + l16) * 32 + (quad ^ (l16 & 3)) * 8];
#pragma unroll
            for (int ni = 0; ni < 2; ni++) {
                acc_l[ni] = __builtin_amdgcn_mfma_f32_16x16x32_bf16(pa[ni], ones, acc_l[ni], 0, 0, 0);
#pragma unroll
                for (int di = 0; di < 4; di++)
                    acc_o[ni][di] = __builtin_amdgcn_mfma_f32_16x16x32_bf16(pa[ni], vb[di], acc_o[ni][di], 0, 0, 0);
            }
        }
        __syncthreads();
    }

    // normalize + store (coalesced along d = di*16 + l16)
#pragma unroll
    for (int ni = 0; ni < 2; ni++) {
#pragma unroll
        for (int r = 0; r < 4; r++) {
            float inv = __builtin_amdgcn_rcpf(acc_l[ni][r]);
            int row = w * 32 + ni * 16 + quad * 4 + r;
#pragma unroll
            for (int di = 0; di < 4; di++)
                Op[(size_t)row * 1024 + di * 16 + l16] = cvt1(acc_o[ni][di][r] * inv);
        }
    }
}

extern "C" void kernel_launch(void* const* d_in, const int* in_sizes, int n_in,
                              void* d_out, int out_size, void* d_ws, size_t ws_size,
                              hipStream_t stream)
{
    (void)in_sizes; (void)n_in; (void)out_size; (void)ws_size;
    // inputs (fp32): 0:x 4:Wq 5:bq 6:Wk 7:bk 8:Wv 9:bv 10:Wo 11:bo
    // 1,2,3,12..19: conditioning — mathematically cancels in softmax.
    const float* xf  = (const float*)d_in[0];
    const float* Wqf = (const float*)d_in[4];  const float* bqf = (const float*)d_in[5];
    const float* Wkf = (const float*)d_in[6];  const float* bkf = (const float*)d_in[7];
    const float* Wvf = (const float*)d_in[8];  const float* bvf = (const float*)d_in[9];
    const float* Wof = (const float*)d_in[10]; const float* bof = (const float*)d_in[11];

    u16* ws  = (u16*)d_ws;
    u16* Qw  = ws;                              // 8M el bf16 (pre-scaled by log2e/8)
    u16* Kw  = ws + (size_t)8388608;            // 8M el bf16
    u16* Vtw = ws + (size_t)16777216;           // 8M el bf16 [b*16+h][64][1024]
    u16* WT  = ws + (size_t)25165824;           // 4M el bf16 [4][n=1024][k=1024]
    u16* xb  = ws + (size_t)29360128;           // 8M el bf16 x; reused as AO after QKV
    u16* AO  = xb;

    k_prep<<<9216, 256, 0, stream>>>(xf, xb, Wqf, Wkf, Wvf, Wof, WT);
    k_gq<<<dim3(8, 64), 256, 0, stream>>>(xb, WT, bqf, Qw);
    k_gk<<<dim3(8, 64), 256, 0, stream>>>(xb, WT, bkf, Kw);
    k_gv<<<dim3(8, 64), 256, 0, stream>>>(xb, WT, bvf, Vtw);
    k_attn<<<dim3(8, 128), 256, 0, stream>>>(Qw, Kw, Vtw, AO);
    k_out4<<<dim3(8, 64), 256, 0, stream>>>(AO, WT + (size_t)3145728, bof, (float*)d_out);
}

// Round 9
// 249.160 us; speedup vs baseline: 1.2028x; 1.0897x over previous
//
#include <hip/hip_runtime.h>

typedef unsigned short u16;
typedef __attribute__((ext_vector_type(4))) unsigned short u16x4;
typedef __attribute__((ext_vector_type(2))) unsigned u32x2;
typedef __attribute__((ext_vector_type(8))) __bf16 bf16x8;
typedef __attribute__((ext_vector_type(2))) __bf16 bf16x2;
typedef __attribute__((ext_vector_type(4))) float f32x4;

#define DEV __device__ __forceinline__

DEV u16 f2b(float f) {
    union { float f; unsigned u; } v; v.f = f;
    unsigned r = v.u + 0x7FFFu + ((v.u >> 16) & 1u);
    return (u16)(r >> 16);
}
DEV unsigned pk2(float a, float b) {   // two f32 -> packed bf16x2 (RNE, hw cvt)
    bf16x2 t; t.x = (__bf16)a; t.y = (__bf16)b;
    union { bf16x2 v; unsigned u; } c; c.v = t; return c.u;
}
DEV u16 cvt1(float f) {
    __bf16 h = (__bf16)f;
    union { __bf16 h; u16 u; } c; c.h = h; return c.u;
}

// async global->LDS, 16B per lane; lds dest = wave-uniform base + lane*16
DEV void gl_lds16(const u16* g, const u16* l) {
    __builtin_amdgcn_global_load_lds(
        (__attribute__((address_space(1))) void*)(unsigned long long)g,
        (__attribute__((address_space(3))) void*)(unsigned long long)l,
        16, 0, 0);
}

// counted-vmcnt phase sync (T4): never drain to 0 in the main loop.
DEV void sync_keep4() {
    asm volatile("s_waitcnt vmcnt(4)" ::: "memory");
    __builtin_amdgcn_s_barrier();
    asm volatile("" ::: "memory");
}
DEV void sync_keep5() {
    asm volatile("s_waitcnt vmcnt(5)" ::: "memory");
    __builtin_amdgcn_s_barrier();
    asm volatile("" ::: "memory");
}
DEV void sync_drain() {
    asm volatile("s_waitcnt vmcnt(0)" ::: "memory");
    __builtin_amdgcn_s_barrier();
    asm volatile("" ::: "memory");
}

// fused prep: blocks [0,8192) convert x fp32->bf16; [8192,9216) transpose W0..3
__global__ __launch_bounds__(256) void k_prep(const float* __restrict__ xf, u16* __restrict__ xb,
                                              const float* w0, const float* w1,
                                              const float* w2, const float* w3,
                                              u16* __restrict__ dst)
{
    __shared__ u16 t[64][68];
    int bx = blockIdx.x;
    if (bx < 8192) {
        size_t base = (size_t)bx * 1024 + threadIdx.x * 4;
        float4 v = *(const float4*)&xf[base];
        u16x4 o; o.x = f2b(v.x); o.y = f2b(v.y); o.z = f2b(v.z); o.w = f2b(v.w);
        *(u16x4*)&xb[base] = o;
        return;
    }
    bx -= 8192;
    int z = bx >> 8, tile = bx & 255;
    const float* src = z == 0 ? w0 : z == 1 ? w1 : z == 2 ? w2 : w3;
    u16* d = dst + (size_t)z * 1048576;
    int tx = threadIdx.x & 15, ty = threadIdx.x >> 4;
    int c0 = (tile & 15) * 64, r0 = (tile >> 4) * 64;
#pragma unroll
    for (int i = 0; i < 4; i++) {
        int r = ty + i * 16;
        float4 v = *(const float4*)&src[(size_t)(r0 + r) * 1024 + c0 + tx * 4];
        t[r][tx * 4 + 0] = f2b(v.x); t[r][tx * 4 + 1] = f2b(v.y);
        t[r][tx * 4 + 2] = f2b(v.z); t[r][tx * 4 + 3] = f2b(v.w);
    }
    __syncthreads();
#pragma unroll
    for (int i = 0; i < 4; i++) {
        int cl = ty + i * 16;
        u16x4 v;
        v.x = t[tx * 4 + 0][cl];
        v.y = t[tx * 4 + 1][cl];
        v.z = t[tx * 4 + 2][cl];
        v.w = t[tx * 4 + 3][cl];
        *(u16x4*)&d[(size_t)(c0 + cl) * 1024 + r0 + tx * 4] = v;
    }
}

// ---------------------------------------------------------------------------
// Fused QKV GEMM (r6-proven, 65.0us measured): 4-wave blocks, 2 blocks/CU,
// ring-4 sub-buffer counted-vmcnt(5) pipeline, pair-row XOR swizzle (0 bank
// conflicts), fused A-sharing (Q,K,V read one staged x tile). BM=128, BN=64
// per matrix, BK=64 as 2x32-k sub-tiles. LDS 80 KB; grid (16,64) = 1024
// blocks = 2.0 rounds. r8 split experiment cost +18us -> refused; r7 B-from-
// L2 regressed 1.8x -> B stays in LDS.
// ---------------------------------------------------------------------------
__global__ __launch_bounds__(256, 2) void k_qkvf(const u16* __restrict__ x, const u16* __restrict__ WT,
                                                 const float* __restrict__ bq, const float* __restrict__ bk,
                                                 const float* __restrict__ bv,
                                                 u16* __restrict__ QK, u16* __restrict__ Vt)
{
    __shared__ u16 lds[40960];
    const int tid = threadIdx.x;
    const int w = tid >> 6, lane = tid & 63, quad = lane >> 4, l16 = lane & 15;
    const int wr = w >> 1, wc = w & 1;              // 2M x 2N wave grid
    const int m0 = blockIdx.y * 128, n0 = blockIdx.x * 64;
    const int K = 1024;

    f32x4 acc[3][4][2] = {};                        // [matrix][mi][ni]

    int srowA[2], skofA[2];
#pragma unroll
    for (int ph = 0; ph < 2; ph++) {
        int L = (ph * 256 + tid) * 8;
        int pr = L >> 6, cp = (L >> 3) & 7;
        int c = cp ^ (pr & 7);
        srowA[ph] = pr * 2 + (c >> 2); skofA[ph] = (c & 3) * 8;
    }
    int LB = tid * 8;
    int prB = LB >> 6, cpB = (LB >> 3) & 7;
    int cB = cpB ^ (prB & 7);
    int srowB = prB * 2 + (cB >> 2), skofB = (cB & 3) * 8;

    const u16* Ap0 = x + ((size_t)m0 + srowA[0]) * K + skofA[0];
    const u16* Ap1 = x + ((size_t)m0 + srowA[1]) * K + skofA[1];
    const u16* Bp0 = WT + ((size_t)n0 + srowB) * K + skofB;   // Wq
    const u16* Bp1 = Bp0 + (size_t)1048576;                   // Wk
    const u16* Bp2 = Bp0 + (size_t)2097152;                   // Wv
    const int wof = w * 512;

    // LDS map (u16): A sub(p,kh) at p*8192+kh*4096, region [0,16384)
    //                B_m sub(p,kh) at 16384 + m*8192 + p*4096 + kh*2048
    auto STAGE = [&](int pb, int t, int kh) {
        size_t ko = (size_t)t * 64 + kh * 32;
        int la = pb * 8192 + kh * 4096 + wof;
        gl_lds16(Ap0 + ko, lds + la);
        gl_lds16(Ap1 + ko, lds + la + 2048);
        int lb = 16384 + pb * 4096 + kh * 2048 + wof;
        gl_lds16(Bp0 + ko, lds + lb);
        gl_lds16(Bp1 + ko, lds + lb + 8192);
        gl_lds16(Bp2 + ko, lds + lb + 16384);
    };

    int aoff[4], boff[2];
#pragma unroll
    for (int mi = 0; mi < 4; mi++) {
        int row = wr * 64 + mi * 16 + l16;
        aoff[mi] = (row >> 1) * 64 + (((((row & 1) << 2) | quad) ^ ((row >> 1) & 7)) << 3);
    }
#pragma unroll
    for (int ni = 0; ni < 2; ni++) {
        int r = wc * 32 + ni * 16 + l16;
        boff[ni] = (r >> 1) * 64 + (((((r & 1) << 2) | quad) ^ ((r >> 1) & 7)) << 3);
    }

    auto LOADF = [&](int pb, int kh, bf16x8 (&a)[4], bf16x8 (&b)[3][2]) {
        const u16* Ab = lds + pb * 8192 + kh * 4096;
        const u16* Bb = lds + 16384 + pb * 4096 + kh * 2048;
#pragma unroll
        for (int mi = 0; mi < 4; mi++) a[mi] = *(const bf16x8*)&Ab[aoff[mi]];
#pragma unroll
        for (int m = 0; m < 3; m++)
#pragma unroll
            for (int ni = 0; ni < 2; ni++)
                b[m][ni] = *(const bf16x8*)&Bb[m * 8192 + boff[ni]];
    };

    auto MM = [&](const bf16x8 (&a)[4], const bf16x8 (&b)[3][2]) {
        __builtin_amdgcn_s_setprio(1);
#pragma unroll
        for (int m = 0; m < 3; m++)
#pragma unroll
            for (int mi = 0; mi < 4; mi++)
#pragma unroll
                for (int ni = 0; ni < 2; ni++)
                    acc[m][mi][ni] = __builtin_amdgcn_mfma_f32_16x16x32_bf16(a[mi], b[m][ni], acc[m][mi][ni], 0, 0, 0);
        __builtin_amdgcn_s_setprio(0);
    };

    // prologue: stage tile 0 fully (10 loads); confirm kh0 quintet
    STAGE(0, 0, 0);
    STAGE(0, 0, 1);
    sync_keep5();

    const int NT = 16;
    for (int t = 0; t < NT - 1; ++t) {
        const int p = t & 1, qb = p ^ 1;
        bf16x8 a[4], b[3][2];
        // phase A (kh=0)
        LOADF(p, 0, a, b);
        STAGE(qb, t + 1, 0);
        sync_keep5();                 // confirms tile t kh1 quintet
        MM(a, b);
        // phase B (kh=1)
        LOADF(p, 1, a, b);
        STAGE(qb, t + 1, 1);
        sync_keep5();                 // confirms tile t+1 kh0 quintet
        MM(a, b);
    }
    {   // last tile: drain
        const int p = (NT - 1) & 1;
        bf16x8 a[4], b[3][2];
        LOADF(p, 0, a, b);
        sync_drain();
        MM(a, b);
        LOADF(p, 1, a, b);
        MM(a, b);
    }

    float bsq[2], bsk[2], bsv2[2];
#pragma unroll
    for (int ni = 0; ni < 2; ni++) {
        int col = n0 + wc * 32 + ni * 16 + l16;
        bsq[ni] = bq[col]; bsk[ni] = bk[col]; bsv2[ni] = bv[col];
    }

    // Q (scaled) and K: row-dense bf16
#pragma unroll
    for (int mi = 0; mi < 4; mi++) {
        int row = m0 + wr * 64 + mi * 16 + quad * 4;
#pragma unroll
        for (int ni = 0; ni < 2; ni++) {
            int col = n0 + wc * 32 + ni * 16 + l16;
#pragma unroll
            for (int r2 = 0; r2 < 4; r2++) {
                QK[(size_t)(row + r2) * 1024 + col] =
                    f2b((acc[0][mi][ni][r2] + bsq[ni]) * 0.18033688011f);
                QK[(size_t)8388608 + (size_t)(row + r2) * 1024 + col] =
                    f2b(acc[1][mi][ni][r2] + bsk[ni]);
            }
        }
    }
    // V: transpose-scatter into Vt [b*16+h][d=64][n=1024]
    {
        int bb = m0 >> 10, nbase = (m0 & 1023) + wr * 64;
#pragma unroll
        for (int mi = 0; mi < 4; mi++) {
            int nrow = nbase + mi * 16 + quad * 4;
#pragma unroll
            for (int ni = 0; ni < 2; ni++) {
                int col = n0 + wc * 32 + ni * 16 + l16;
                int hh = col >> 6, dd = col & 63;
                u16x4 pk;
                pk.x = f2b(acc[2][mi][ni][0] + bsv2[ni]);
                pk.y = f2b(acc[2][mi][ni][1] + bsv2[ni]);
                pk.z = f2b(acc[2][mi][ni][2] + bsv2[ni]);
                pk.w = f2b(acc[2][mi][ni][3] + bsv2[ni]);
                *(u16x4*)&Vt[(size_t)(bb * 16 + hh) * 65536 + (size_t)dd * 1024 + nrow] = pk;
            }
        }
    }
}

// ---------------------------------------------------------------------------
// output projection (fp32 out, r6-proven): 4-wave blocks, BM=128 BN=128,
// ring-4 counted-vmcnt(4), LDS 64 KB -> 2 blocks/CU. Grid (8,64).
// ---------------------------------------------------------------------------
__global__ __launch_bounds__(256, 2) void k_out4(const u16* __restrict__ A, const u16* __restrict__ WoT,
                                                 const float* __restrict__ bo, float* __restrict__ C)
{
    __shared__ u16 lds[32768];
    const int tid = threadIdx.x;
    const int w = tid >> 6, lane = tid & 63, quad = lane >> 4, l16 = lane & 15;
    const int wr = w >> 1, wc = w & 1;
    const int m0 = blockIdx.y * 128, n0 = blockIdx.x * 128;
    const int K = 1024;

    f32x4 acc[4][4] = {};

    int srowA[2], skofA[2];
#pragma unroll
    for (int ph = 0; ph < 2; ph++) {
        int L = (ph * 256 + tid) * 8;
        int pr = L >> 6, cp = (L >> 3) & 7;
        int c = cp ^ (pr & 7);
        srowA[ph] = pr * 2 + (c >> 2); skofA[ph] = (c & 3) * 8;
    }
    const u16* Ap0 = A + ((size_t)m0 + srowA[0]) * K + skofA[0];
    const u16* Ap1 = A + ((size_t)m0 + srowA[1]) * K + skofA[1];
    const u16* Bq0 = WoT + ((size_t)n0 + srowA[0]) * K + skofA[0];
    const u16* Bq1 = WoT + ((size_t)n0 + srowA[1]) * K + skofA[1];
    const int wof = w * 512;

    auto STAGE = [&](int pb, int t, int kh) {
        size_t ko = (size_t)t * 64 + kh * 32;
        int la = pb * 8192 + kh * 4096 + wof;
        gl_lds16(Ap0 + ko, lds + la);
        gl_lds16(Ap1 + ko, lds + la + 2048);
        gl_lds16(Bq0 + ko, lds + 16384 + la);
        gl_lds16(Bq1 + ko, lds + 16384 + la + 2048);
    };

    int aoff[4], boff[4];
#pragma unroll
    for (int mi = 0; mi < 4; mi++) {
        int row = wr * 64 + mi * 16 + l16;
        aoff[mi] = (row >> 1) * 64 + (((((row & 1) << 2) | quad) ^ ((row >> 1) & 7)) << 3);
    }
#pragma unroll
    for (int ni = 0; ni < 4; ni++) {
        int r = wc * 64 + ni * 16 + l16;
        boff[ni] = (r >> 1) * 64 + (((((r & 1) << 2) | quad) ^ ((r >> 1) & 7)) << 3);
    }

    auto LOADF = [&](int pb, int kh, bf16x8 (&a)[4], bf16x8 (&b)[4]) {
        const u16* Ab = lds + pb * 8192 + kh * 4096;
        const u16* Bb = lds + 16384 + pb * 8192 + kh * 4096;
#pragma unroll
        for (int mi = 0; mi < 4; mi++) a[mi] = *(const bf16x8*)&Ab[aoff[mi]];
#pragma unroll
        for (int ni = 0; ni < 4; ni++) b[ni] = *(const bf16x8*)&Bb[boff[ni]];
    };

    auto MM = [&](const bf16x8 (&a)[4], const bf16x8 (&b)[4]) {
        __builtin_amdgcn_s_setprio(1);
#pragma unroll
        for (int mi = 0; mi < 4; mi++)
#pragma unroll
            for (int ni = 0; ni < 4; ni++)
                acc[mi][ni] = __builtin_amdgcn_mfma_f32_16x16x32_bf16(a[mi], b[ni], acc[mi][ni], 0, 0, 0);
        __builtin_amdgcn_s_setprio(0);
    };

    STAGE(0, 0, 0);
    STAGE(0, 0, 1);
    sync_keep4();

    const int NT = 16;
    for (int t = 0; t < NT - 1; ++t) {
        const int p = t & 1, qb = p ^ 1;
        bf16x8 a[4], b[4];
        LOADF(p, 0, a, b);
        STAGE(qb, t + 1, 0);
        sync_keep4();
        MM(a, b);
        LOADF(p, 1, a, b);
        STAGE(qb, t + 1, 1);
        sync_keep4();
        MM(a, b);
    }
    {
        const int p = (NT - 1) & 1;
        bf16x8 a[4], b[4];
        LOADF(p, 0, a, b);
        sync_drain();
        MM(a, b);
        LOADF(p, 1, a, b);
        MM(a, b);
    }

    float bs[4];
#pragma unroll
    for (int ni = 0; ni < 4; ni++)
        bs[ni] = bo[n0 + wc * 64 + ni * 16 + l16];
#pragma unroll
    for (int mi = 0; mi < 4; mi++) {
        int row = m0 + wr * 64 + mi * 16 + quad * 4;
#pragma unroll
        for (int ni = 0; ni < 4; ni++) {
            int col = n0 + wc * 64 + ni * 16 + l16;
#pragma unroll
            for (int r2 = 0; r2 < 4; r2++)
                C[(size_t)(row + r2) * 1024 + col] = acc[mi][ni][r2] + bs[ni];
        }
    }
}

// ---------------------------------------------------------------------------
// attention v7 = v5 + XCD-locality grid swap. r8 counters: FETCH 139MB
// (~3x ideal), HBM 37% peak. Old grid (8,128) id=qtile+8*bh put the 8
// q-tiles of each (b,h) on 8 DIFFERENT XCDs -> every K/V slice fetched 8x,
// 32MB working set per 4MB L2. New grid (128,8) id=bh+128*qtile: id%8=bh%8
// -> all 8 q-tiles of one (b,h) on the SAME XCD; 16 bh-groups x 256KB = 4MB
// = exactly L2. All 1024 blocks co-resident (4/CU). Kernel body unchanged.
// ---------------------------------------------------------------------------
__global__ __launch_bounds__(256, 4) void k_attn(const u16* __restrict__ Q, const u16* __restrict__ K,
                                                 const u16* __restrict__ Vt, u16* __restrict__ O)
{
    __shared__ u16 lds[13312];
    const int tid = threadIdx.x, w = tid >> 6, lane = tid & 63, quad = lane >> 4, l16 = lane & 15;
    const int bh = blockIdx.x, b = bh >> 4, h = bh & 15;   // XCD swizzle: bh on x
    const int q0 = blockIdx.y * 128;
    const u16* Qp = Q + ((size_t)b * 1024 + q0) * 1024 + h * 64;
    const u16* Kp = K + (size_t)b * 1048576 + h * 64;
    const u16* Vp = Vt + (size_t)bh * 65536;
    u16* Op = O + ((size_t)b * 1024 + q0) * 1024 + h * 64;
    u16* Pw = lds + 8192 + w * 1280;   // 32 rows x 40 u16, wave-private

    // stage Q [128][64] swizzled into [0,8192)
#pragma unroll
    for (int i = 0; i < 4; i++) {
        int g = (w * 4 + i) * 64 + lane;
        int row = g >> 3, c = (g & 7) ^ (row & 7);
        gl_lds16(Qp + (size_t)row * 1024 + c * 8, lds + (w * 4 + i) * 512);
    }
    __syncthreads();
    bf16x8 qa[2][2];
#pragma unroll
    for (int ni = 0; ni < 2; ni++)
#pragma unroll
        for (int d2 = 0; d2 < 2; d2++)
            qa[ni][d2] = *(const bf16x8*)&lds[(w * 32 + ni * 16 + l16) * 64 + ((d2 * 4 + quad) ^ (l16 & 7)) * 8];
    __syncthreads();   // all waves done reading Q before KV staging overwrites it

    // stage kt0 into buf0
    {
        int g = w * 64 + lane;
        int row = g >> 3, c = (g & 7) ^ (row & 7);
        gl_lds16(Kp + (size_t)row * 1024 + c * 8, lds + w * 512);
        int rv = g >> 2, cv = (g & 3) ^ (rv & 3);
        gl_lds16(Vp + (size_t)rv * 1024 + cv * 8, lds + 2048 + w * 512);
    }
    __syncthreads();

    bf16x8 ones;
#pragma unroll
    for (int j = 0; j < 8; j++) ones[j] = (__bf16)1.0f;

    f32x4 acc_o[2][4] = {};   // [ni][di]: D[q][d], col=d(l16), row=q-part
    f32x4 acc_l[2] = {};      // [ni]: l(q), row-aligned with acc_o

    for (int kt = 0; kt < 32; kt++) {
        const u16* buf = lds + (kt & 1) * 4096;
        if (kt < 31) {
            int k0n = (kt + 1) * 32;
            u16* dst = lds + ((kt + 1) & 1) * 4096;
            int g = w * 64 + lane;
            int row = g >> 3, c = (g & 7) ^ (row & 7);
            gl_lds16(Kp + (size_t)(k0n + row) * 1024 + c * 8, dst + w * 512);
            int rv = g >> 2, cv = (g & 3) ^ (rv & 3);
            gl_lds16(Vp + (size_t)rv * 1024 + k0n + cv * 8, dst + 2048 + w * 512);
        }

        // S^T: D[k=mi*16+quad*4+reg][q=w*32+ni*16+l16], accumulate over d halves
        f32x4 s[2][2] = {};
#pragma unroll
        for (int d2 = 0; d2 < 2; d2++) {
            bf16x8 ka[2];
#pragma unroll
            for (int mi = 0; mi < 2; mi++)
                ka[mi] = *(const bf16x8*)&buf[(mi * 16 + l16) * 64 + ((d2 * 4 + quad) ^ (l16 & 7)) * 8];
#pragma unroll
            for (int mi = 0; mi < 2; mi++)
#pragma unroll
                for (int ni = 0; ni < 2; ni++)
                    s[mi][ni] = __builtin_amdgcn_mfma_f32_16x16x32_bf16(ka[mi], qa[ni][d2], s[mi][ni], 0, 0, 0);
        }

        // exp2 (Q pre-scaled), pack 4 consecutive k -> wave-private Ps
#pragma unroll
        for (int ni = 0; ni < 2; ni++)
#pragma unroll
            for (int mi = 0; mi < 2; mi++) {
                float e0 = __builtin_amdgcn_exp2f(s[mi][ni][0]);
                float e1 = __builtin_amdgcn_exp2f(s[mi][ni][1]);
                float e2 = __builtin_amdgcn_exp2f(s[mi][ni][2]);
                float e3 = __builtin_amdgcn_exp2f(s[mi][ni][3]);
                u32x2 pk; pk.x = pk2(e0, e1); pk.y = pk2(e2, e3);
                *(u32x2*)&Pw[(ni * 16 + l16) * 40 + mi * 16 + quad * 4] = pk;
            }

        // O[q][d] += P[q][k32] V[k32][d]; l(q) += P*ones; same-wave LDS RAW
        {
            bf16x8 pa[2], vb[4];
#pragma unroll
            for (int ni = 0; ni < 2; ni++)
                pa[ni] = *(const bf16x8*)&Pw[(ni * 16 + l16) * 40 + quad * 8];
#pragma unroll
            for (int di = 0; di < 4; di++)
                vb[di] = *(const bf16x8*)&buf[2048 + (di * 16 + l16) * 32 + (quad ^ (l16 & 3)) * 8];
#pragma unroll
            for (int ni = 0; ni < 2; ni++) {
                acc_l[ni] = __builtin_amdgcn_mfma_f32_16x16x32_bf16(pa[ni], ones, acc_l[ni], 0, 0, 0);
#pragma unroll
                for (int di = 0; di < 4; di++)
                    acc_o[ni][di] = __builtin_amdgcn_mfma_f32_16x16x32_bf16(pa[ni], vb[di], acc_o[ni][di], 0, 0, 0);
            }
        }
        __syncthreads();
    }

    // normalize + store (coalesced along d = di*16 + l16)
#pragma unroll
    for (int ni = 0; ni < 2; ni++) {
#pragma unroll
        for (int r = 0; r < 4; r++) {
            float inv = __builtin_amdgcn_rcpf(acc_l[ni][r]);
            int row = w * 32 + ni * 16 + quad * 4 + r;
#pragma unroll
            for (int di = 0; di < 4; di++)
                Op[(size_t)row * 1024 + di * 16 + l16] = cvt1(acc_o[ni][di][r] * inv);
        }
    }
}

extern "C" void kernel_launch(void* const* d_in, const int* in_sizes, int n_in,
                              void* d_out, int out_size, void* d_ws, size_t ws_size,
                              hipStream_t stream)
{
    (void)in_sizes; (void)n_in; (void)out_size; (void)ws_size;
    // inputs (fp32): 0:x 4:Wq 5:bq 6:Wk 7:bk 8:Wv 9:bv 10:Wo 11:bo
    // 1,2,3,12..19: conditioning — mathematically cancels in softmax.
    const float* xf  = (const float*)d_in[0];
    const float* Wqf = (const float*)d_in[4];  const float* bqf = (const float*)d_in[5];
    const float* Wkf = (const float*)d_in[6];  const float* bkf = (const float*)d_in[7];
    const float* Wvf = (const float*)d_in[8];  const float* bvf = (const float*)d_in[9];
    const float* Wof = (const float*)d_in[10]; const float* bof = (const float*)d_in[11];

    u16* ws  = (u16*)d_ws;
    u16* Qw  = ws;                              // 8M el bf16 (pre-scaled by log2e/8)
    u16* Kw  = ws + (size_t)8388608;            // 8M el bf16
    u16* Vtw = ws + (size_t)16777216;           // 8M el bf16 [b*16+h][64][1024]
    u16* WT  = ws + (size_t)25165824;           // 4M el bf16 [4][n=1024][k=1024]
    u16* xb  = ws + (size_t)29360128;           // 8M el bf16 x; reused as AO after k_qkv
    u16* AO  = xb;

    k_prep<<<9216, 256, 0, stream>>>(xf, xb, Wqf, Wkf, Wvf, Wof, WT);
    k_qkvf<<<dim3(16, 64), 256, 0, stream>>>(xb, WT, bqf, bkf, bvf, Qw, Vtw);
    k_attn<<<dim3(128, 8), 256, 0, stream>>>(Qw, Kw, Vtw, AO);
    k_out4<<<dim3(8, 64), 256, 0, stream>>>(AO, WT + (size_t)3145728, bof, (float*)d_out);
}

// Round 10
// 244.686 us; speedup vs baseline: 1.2248x; 1.0183x over previous
//
#include <hip/hip_runtime.h>

typedef unsigned short u16;
typedef __attribute__((ext_vector_type(4))) unsigned short u16x4;
typedef __attribute__((ext_vector_type(2))) unsigned u32x2;
typedef __attribute__((ext_vector_type(8))) __bf16 bf16x8;
typedef __attribute__((ext_vector_type(2))) __bf16 bf16x2;
typedef __attribute__((ext_vector_type(4))) float f32x4;

#define DEV __device__ __forceinline__

DEV u16 f2b(float f) {
    union { float f; unsigned u; } v; v.f = f;
    unsigned r = v.u + 0x7FFFu + ((v.u >> 16) & 1u);
    return (u16)(r >> 16);
}
DEV unsigned pk2(float a, float b) {   // two f32 -> packed bf16x2 (RNE, hw cvt)
    bf16x2 t; t.x = (__bf16)a; t.y = (__bf16)b;
    union { bf16x2 v; unsigned u; } c; c.v = t; return c.u;
}
DEV u16 cvt1(float f) {
    __bf16 h = (__bf16)f;
    union { __bf16 h; u16 u; } c; c.h = h; return c.u;
}

// async global->LDS, 16B per lane; lds dest = wave-uniform base + lane*16
DEV void gl_lds16(const u16* g, const u16* l) {
    __builtin_amdgcn_global_load_lds(
        (__attribute__((address_space(1))) void*)(unsigned long long)g,
        (__attribute__((address_space(3))) void*)(unsigned long long)l,
        16, 0, 0);
}

// counted-vmcnt phase sync (T4): never drain to 0 in the main loop.
DEV void sync_keep4() {
    asm volatile("s_waitcnt vmcnt(4)" ::: "memory");
    __builtin_amdgcn_s_barrier();
    asm volatile("" ::: "memory");
}
DEV void sync_keep5() {
    asm volatile("s_waitcnt vmcnt(5)" ::: "memory");
    __builtin_amdgcn_s_barrier();
    asm volatile("" ::: "memory");
}
DEV void sync_drain() {
    asm volatile("s_waitcnt vmcnt(0)" ::: "memory");
    __builtin_amdgcn_s_barrier();
    asm volatile("" ::: "memory");
}

// fused prep: blocks [0,8192) convert x fp32->bf16; [8192,9216) transpose W0..3
__global__ __launch_bounds__(256) void k_prep(const float* __restrict__ xf, u16* __restrict__ xb,
                                              const float* w0, const float* w1,
                                              const float* w2, const float* w3,
                                              u16* __restrict__ dst)
{
    __shared__ u16 t[64][68];
    int bx = blockIdx.x;
    if (bx < 8192) {
        size_t base = (size_t)bx * 1024 + threadIdx.x * 4;
        float4 v = *(const float4*)&xf[base];
        u16x4 o; o.x = f2b(v.x); o.y = f2b(v.y); o.z = f2b(v.z); o.w = f2b(v.w);
        *(u16x4*)&xb[base] = o;
        return;
    }
    bx -= 8192;
    int z = bx >> 8, tile = bx & 255;
    const float* src = z == 0 ? w0 : z == 1 ? w1 : z == 2 ? w2 : w3;
    u16* d = dst + (size_t)z * 1048576;
    int tx = threadIdx.x & 15, ty = threadIdx.x >> 4;
    int c0 = (tile & 15) * 64, r0 = (tile >> 4) * 64;
#pragma unroll
    for (int i = 0; i < 4; i++) {
        int r = ty + i * 16;
        float4 v = *(const float4*)&src[(size_t)(r0 + r) * 1024 + c0 + tx * 4];
        t[r][tx * 4 + 0] = f2b(v.x); t[r][tx * 4 + 1] = f2b(v.y);
        t[r][tx * 4 + 2] = f2b(v.z); t[r][tx * 4 + 3] = f2b(v.w);
    }
    __syncthreads();
#pragma unroll
    for (int i = 0; i < 4; i++) {
        int cl = ty + i * 16;
        u16x4 v;
        v.x = t[tx * 4 + 0][cl];
        v.y = t[tx * 4 + 1][cl];
        v.z = t[tx * 4 + 2][cl];
        v.w = t[tx * 4 + 3][cl];
        *(u16x4*)&d[(size_t)(c0 + cl) * 1024 + r0 + tx * 4] = v;
    }
}

// ---------------------------------------------------------------------------
// Fused QKV GEMM (r6-proven): 4-wave blocks, 2 blocks/CU, ring-4 sub-buffer
// counted-vmcnt(5) pipeline, pair-row XOR swizzle (0 bank conflicts), fused
// A-sharing. BM=128, BN=64 per matrix, BK=64. LDS 80 KB; grid (16,64).
// Measured 65.0us (r6) / 70.5us (r9, same code — cross-session variance).
// ---------------------------------------------------------------------------
__global__ __launch_bounds__(256, 2) void k_qkvf(const u16* __restrict__ x, const u16* __restrict__ WT,
                                                 const float* __restrict__ bq, const float* __restrict__ bk,
                                                 const float* __restrict__ bv,
                                                 u16* __restrict__ QK, u16* __restrict__ Vt)
{
    __shared__ u16 lds[40960];
    const int tid = threadIdx.x;
    const int w = tid >> 6, lane = tid & 63, quad = lane >> 4, l16 = lane & 15;
    const int wr = w >> 1, wc = w & 1;              // 2M x 2N wave grid
    const int m0 = blockIdx.y * 128, n0 = blockIdx.x * 64;
    const int K = 1024;

    f32x4 acc[3][4][2] = {};                        // [matrix][mi][ni]

    int srowA[2], skofA[2];
#pragma unroll
    for (int ph = 0; ph < 2; ph++) {
        int L = (ph * 256 + tid) * 8;
        int pr = L >> 6, cp = (L >> 3) & 7;
        int c = cp ^ (pr & 7);
        srowA[ph] = pr * 2 + (c >> 2); skofA[ph] = (c & 3) * 8;
    }
    int LB = tid * 8;
    int prB = LB >> 6, cpB = (LB >> 3) & 7;
    int cB = cpB ^ (prB & 7);
    int srowB = prB * 2 + (cB >> 2), skofB = (cB & 3) * 8;

    const u16* Ap0 = x + ((size_t)m0 + srowA[0]) * K + skofA[0];
    const u16* Ap1 = x + ((size_t)m0 + srowA[1]) * K + skofA[1];
    const u16* Bp0 = WT + ((size_t)n0 + srowB) * K + skofB;   // Wq
    const u16* Bp1 = Bp0 + (size_t)1048576;                   // Wk
    const u16* Bp2 = Bp0 + (size_t)2097152;                   // Wv
    const int wof = w * 512;

    // LDS map (u16): A sub(p,kh) at p*8192+kh*4096, region [0,16384)
    //                B_m sub(p,kh) at 16384 + m*8192 + p*4096 + kh*2048
    auto STAGE = [&](int pb, int t, int kh) {
        size_t ko = (size_t)t * 64 + kh * 32;
        int la = pb * 8192 + kh * 4096 + wof;
        gl_lds16(Ap0 + ko, lds + la);
        gl_lds16(Ap1 + ko, lds + la + 2048);
        int lb = 16384 + pb * 4096 + kh * 2048 + wof;
        gl_lds16(Bp0 + ko, lds + lb);
        gl_lds16(Bp1 + ko, lds + lb + 8192);
        gl_lds16(Bp2 + ko, lds + lb + 16384);
    };

    int aoff[4], boff[2];
#pragma unroll
    for (int mi = 0; mi < 4; mi++) {
        int row = wr * 64 + mi * 16 + l16;
        aoff[mi] = (row >> 1) * 64 + (((((row & 1) << 2) | quad) ^ ((row >> 1) & 7)) << 3);
    }
#pragma unroll
    for (int ni = 0; ni < 2; ni++) {
        int r = wc * 32 + ni * 16 + l16;
        boff[ni] = (r >> 1) * 64 + (((((r & 1) << 2) | quad) ^ ((r >> 1) & 7)) << 3);
    }

    auto LOADF = [&](int pb, int kh, bf16x8 (&a)[4], bf16x8 (&b)[3][2]) {
        const u16* Ab = lds + pb * 8192 + kh * 4096;
        const u16* Bb = lds + 16384 + pb * 4096 + kh * 2048;
#pragma unroll
        for (int mi = 0; mi < 4; mi++) a[mi] = *(const bf16x8*)&Ab[aoff[mi]];
#pragma unroll
        for (int m = 0; m < 3; m++)
#pragma unroll
            for (int ni = 0; ni < 2; ni++)
                b[m][ni] = *(const bf16x8*)&Bb[m * 8192 + boff[ni]];
    };

    auto MM = [&](const bf16x8 (&a)[4], const bf16x8 (&b)[3][2]) {
        __builtin_amdgcn_s_setprio(1);
#pragma unroll
        for (int m = 0; m < 3; m++)
#pragma unroll
            for (int mi = 0; mi < 4; mi++)
#pragma unroll
                for (int ni = 0; ni < 2; ni++)
                    acc[m][mi][ni] = __builtin_amdgcn_mfma_f32_16x16x32_bf16(a[mi], b[m][ni], acc[m][mi][ni], 0, 0, 0);
        __builtin_amdgcn_s_setprio(0);
    };

    // prologue: stage tile 0 fully (10 loads); confirm kh0 quintet
    STAGE(0, 0, 0);
    STAGE(0, 0, 1);
    sync_keep5();

    const int NT = 16;
    for (int t = 0; t < NT - 1; ++t) {
        const int p = t & 1, qb = p ^ 1;
        bf16x8 a[4], b[3][2];
        // phase A (kh=0)
        LOADF(p, 0, a, b);
        STAGE(qb, t + 1, 0);
        sync_keep5();                 // confirms tile t kh1 quintet
        MM(a, b);
        // phase B (kh=1)
        LOADF(p, 1, a, b);
        STAGE(qb, t + 1, 1);
        sync_keep5();                 // confirms tile t+1 kh0 quintet
        MM(a, b);
    }
    {   // last tile: drain
        const int p = (NT - 1) & 1;
        bf16x8 a[4], b[3][2];
        LOADF(p, 0, a, b);
        sync_drain();
        MM(a, b);
        LOADF(p, 1, a, b);
        MM(a, b);
    }

    float bsq[2], bsk[2], bsv2[2];
#pragma unroll
    for (int ni = 0; ni < 2; ni++) {
        int col = n0 + wc * 32 + ni * 16 + l16;
        bsq[ni] = bq[col]; bsk[ni] = bk[col]; bsv2[ni] = bv[col];
    }

    // Q (scaled) and K: row-dense bf16
#pragma unroll
    for (int mi = 0; mi < 4; mi++) {
        int row = m0 + wr * 64 + mi * 16 + quad * 4;
#pragma unroll
        for (int ni = 0; ni < 2; ni++) {
            int col = n0 + wc * 32 + ni * 16 + l16;
#pragma unroll
            for (int r2 = 0; r2 < 4; r2++) {
                QK[(size_t)(row + r2) * 1024 + col] =
                    f2b((acc[0][mi][ni][r2] + bsq[ni]) * 0.18033688011f);
                QK[(size_t)8388608 + (size_t)(row + r2) * 1024 + col] =
                    f2b(acc[1][mi][ni][r2] + bsk[ni]);
            }
        }
    }
    // V: transpose-scatter into Vt [b*16+h][d=64][n=1024]
    {
        int bb = m0 >> 10, nbase = (m0 & 1023) + wr * 64;
#pragma unroll
        for (int mi = 0; mi < 4; mi++) {
            int nrow = nbase + mi * 16 + quad * 4;
#pragma unroll
            for (int ni = 0; ni < 2; ni++) {
                int col = n0 + wc * 32 + ni * 16 + l16;
                int hh = col >> 6, dd = col & 63;
                u16x4 pk;
                pk.x = f2b(acc[2][mi][ni][0] + bsv2[ni]);
                pk.y = f2b(acc[2][mi][ni][1] + bsv2[ni]);
                pk.z = f2b(acc[2][mi][ni][2] + bsv2[ni]);
                pk.w = f2b(acc[2][mi][ni][3] + bsv2[ni]);
                *(u16x4*)&Vt[(size_t)(bb * 16 + hh) * 65536 + (size_t)dd * 1024 + nrow] = pk;
            }
        }
    }
}

// ---------------------------------------------------------------------------
// output projection (fp32 out, r6-proven): 4-wave blocks, BM=128 BN=128,
// ring-4 counted-vmcnt(4), LDS 64 KB -> 2 blocks/CU. Grid (8,64).
// ---------------------------------------------------------------------------
__global__ __launch_bounds__(256, 2) void k_out4(const u16* __restrict__ A, const u16* __restrict__ WoT,
                                                 const float* __restrict__ bo, float* __restrict__ C)
{
    __shared__ u16 lds[32768];
    const int tid = threadIdx.x;
    const int w = tid >> 6, lane = tid & 63, quad = lane >> 4, l16 = lane & 15;
    const int wr = w >> 1, wc = w & 1;
    const int m0 = blockIdx.y * 128, n0 = blockIdx.x * 128;
    const int K = 1024;

    f32x4 acc[4][4] = {};

    int srowA[2], skofA[2];
#pragma unroll
    for (int ph = 0; ph < 2; ph++) {
        int L = (ph * 256 + tid) * 8;
        int pr = L >> 6, cp = (L >> 3) & 7;
        int c = cp ^ (pr & 7);
        srowA[ph] = pr * 2 + (c >> 2); skofA[ph] = (c & 3) * 8;
    }
    const u16* Ap0 = A + ((size_t)m0 + srowA[0]) * K + skofA[0];
    const u16* Ap1 = A + ((size_t)m0 + srowA[1]) * K + skofA[1];
    const u16* Bq0 = WoT + ((size_t)n0 + srowA[0]) * K + skofA[0];
    const u16* Bq1 = WoT + ((size_t)n0 + srowA[1]) * K + skofA[1];
    const int wof = w * 512;

    auto STAGE = [&](int pb, int t, int kh) {
        size_t ko = (size_t)t * 64 + kh * 32;
        int la = pb * 8192 + kh * 4096 + wof;
        gl_lds16(Ap0 + ko, lds + la);
        gl_lds16(Ap1 + ko, lds + la + 2048);
        gl_lds16(Bq0 + ko, lds + 16384 + la);
        gl_lds16(Bq1 + ko, lds + 16384 + la + 2048);
    };

    int aoff[4], boff[4];
#pragma unroll
    for (int mi = 0; mi < 4; mi++) {
        int row = wr * 64 + mi * 16 + l16;
        aoff[mi] = (row >> 1) * 64 + (((((row & 1) << 2) | quad) ^ ((row >> 1) & 7)) << 3);
    }
#pragma unroll
    for (int ni = 0; ni < 4; ni++) {
        int r = wc * 64 + ni * 16 + l16;
        boff[ni] = (r >> 1) * 64 + (((((r & 1) << 2) | quad) ^ ((r >> 1) & 7)) << 3);
    }

    auto LOADF = [&](int pb, int kh, bf16x8 (&a)[4], bf16x8 (&b)[4]) {
        const u16* Ab = lds + pb * 8192 + kh * 4096;
        const u16* Bb = lds + 16384 + pb * 8192 + kh * 4096;
#pragma unroll
        for (int mi = 0; mi < 4; mi++) a[mi] = *(const bf16x8*)&Ab[aoff[mi]];
#pragma unroll
        for (int ni = 0; ni < 4; ni++) b[ni] = *(const bf16x8*)&Bb[boff[ni]];
    };

    auto MM = [&](const bf16x8 (&a)[4], const bf16x8 (&b)[4]) {
        __builtin_amdgcn_s_setprio(1);
#pragma unroll
        for (int mi = 0; mi < 4; mi++)
#pragma unroll
            for (int ni = 0; ni < 4; ni++)
                acc[mi][ni] = __builtin_amdgcn_mfma_f32_16x16x32_bf16(a[mi], b[ni], acc[mi][ni], 0, 0, 0);
        __builtin_amdgcn_s_setprio(0);
    };

    STAGE(0, 0, 0);
    STAGE(0, 0, 1);
    sync_keep4();

    const int NT = 16;
    for (int t = 0; t < NT - 1; ++t) {
        const int p = t & 1, qb = p ^ 1;
        bf16x8 a[4], b[4];
        LOADF(p, 0, a, b);
        STAGE(qb, t + 1, 0);
        sync_keep4();
        MM(a, b);
        LOADF(p, 1, a, b);
        STAGE(qb, t + 1, 1);
        sync_keep4();
        MM(a, b);
    }
    {
        const int p = (NT - 1) & 1;
        bf16x8 a[4], b[4];
        LOADF(p, 0, a, b);
        sync_drain();
        MM(a, b);
        LOADF(p, 1, a, b);
        MM(a, b);
    }

    float bs[4];
#pragma unroll
    for (int ni = 0; ni < 4; ni++)
        bs[ni] = bo[n0 + wc * 64 + ni * 16 + l16];
#pragma unroll
    for (int mi = 0; mi < 4; mi++) {
        int row = m0 + wr * 64 + mi * 16 + quad * 4;
#pragma unroll
        for (int ni = 0; ni < 4; ni++) {
            int col = n0 + wc * 64 + ni * 16 + l16;
#pragma unroll
            for (int r2 = 0; r2 < 4; r2++)
                C[(size_t)(row + r2) * 1024 + col] = acc[mi][ni][r2] + bs[ni];
        }
    }
}

// ---------------------------------------------------------------------------
// attention v8 = v7 (XCD grid swap, confirmed r9: total -4.5us, attn out of
// top-5) + conflict-free V block permutation. r8 counters: 5.24M bank-conflict
// cycles = the V-read: [64 d][32 k] stride-64B rows give bank = (l16&1)*16 +
// chunk*4 -> only 8 start positions for 64 lanes = 8-way. Pad is impossible
// (gl_lds16 linear dest, rule #21), but the staging SOURCE is per-lane, so
// permute 16B blocks: block(d, kc) at index j = (d&7) + 8*((d>>3)*4 + kc).
// Read start-bank becomes (l16&7)*4 -> 8 positions x 2 lanes = free.
// Same bytes, same HBM pattern (16 rows x 64B per wave). K/Q/P verified
// conflict-free by the same arithmetic (2-way max).
// ---------------------------------------------------------------------------
__global__ __launch_bounds__(256, 4) void k_attn(const u16* __restrict__ Q, const u16* __restrict__ K,
                                                 const u16* __restrict__ Vt, u16* __restrict__ O)
{
    __shared__ u16 lds[13312];
    const int tid = threadIdx.x, w = tid >> 6, lane = tid & 63, quad = lane >> 4, l16 = lane & 15;
    const int bh = blockIdx.x, b = bh >> 4, h = bh & 15;   // XCD swizzle: bh on x
    const int q0 = blockIdx.y * 128;
    const u16* Qp = Q + ((size_t)b * 1024 + q0) * 1024 + h * 64;
    const u16* Kp = K + (size_t)b * 1048576 + h * 64;
    const u16* Vp = Vt + (size_t)bh * 65536;
    u16* Op = O + ((size_t)b * 1024 + q0) * 1024 + h * 64;
    u16* Pw = lds + 8192 + w * 1280;   // 32 rows x 40 u16, wave-private

    // stage Q [128][64] swizzled into [0,8192)
#pragma unroll
    for (int i = 0; i < 4; i++) {
        int g = (w * 4 + i) * 64 + lane;
        int row = g >> 3, c = (g & 7) ^ (row & 7);
        gl_lds16(Qp + (size_t)row * 1024 + c * 8, lds + (w * 4 + i) * 512);
    }
    __syncthreads();
    bf16x8 qa[2][2];
#pragma unroll
    for (int ni = 0; ni < 2; ni++)
#pragma unroll
        for (int d2 = 0; d2 < 2; d2++)
            qa[ni][d2] = *(const bf16x8*)&lds[(w * 32 + ni * 16 + l16) * 64 + ((d2 * 4 + quad) ^ (l16 & 7)) * 8];
    __syncthreads();   // all waves done reading Q before KV staging overwrites it

    // V block-permutation indices: lane g holds block j=g -> (d, kc)
    const int gg = w * 64 + lane;
    const int dv = ((gg >> 5) << 3) + (gg & 7);   // d row in Vt
    const int kc = (gg >> 3) & 3;                 // k chunk (8 u16)

    // stage kt0 into buf0
    {
        int g = gg;
        int row = g >> 3, c = (g & 7) ^ (row & 7);
        gl_lds16(Kp + (size_t)row * 1024 + c * 8, lds + w * 512);
        gl_lds16(Vp + (size_t)dv * 1024 + kc * 8, lds + 2048 + w * 512);
    }
    __syncthreads();

    bf16x8 ones;
#pragma unroll
    for (int j = 0; j < 8; j++) ones[j] = (__bf16)1.0f;

    f32x4 acc_o[2][4] = {};   // [ni][di]: D[q][d], col=d(l16), row=q-part
    f32x4 acc_l[2] = {};      // [ni]: l(q), row-aligned with acc_o

    // V read offset: block (d=di*16+l16, kc=quad) at u16 off
    //   2048 + (l16&7)*8 + 512*di + 256*(l16>>3) + 64*quad
    const int vbase = 2048 + (l16 & 7) * 8 + 256 * (l16 >> 3) + 64 * quad;

    for (int kt = 0; kt < 32; kt++) {
        const u16* buf = lds + (kt & 1) * 4096;
        if (kt < 31) {
            int k0n = (kt + 1) * 32;
            u16* dst = lds + ((kt + 1) & 1) * 4096;
            int g = gg;
            int row = g >> 3, c = (g & 7) ^ (row & 7);
            gl_lds16(Kp + (size_t)(k0n + row) * 1024 + c * 8, dst + w * 512);
            gl_lds16(Vp + (size_t)dv * 1024 + k0n + kc * 8, dst + 2048 + w * 512);
        }

        // S^T: D[k=mi*16+quad*4+reg][q=w*32+ni*16+l16], accumulate over d halves
        f32x4 s[2][2] = {};
#pragma unroll
        for (int d2 = 0; d2 < 2; d2++) {
            bf16x8 ka[2];
#pragma unroll
            for (int mi = 0; mi < 2; mi++)
                ka[mi] = *(const bf16x8*)&buf[(mi * 16 + l16) * 64 + ((d2 * 4 + quad) ^ (l16 & 7)) * 8];
#pragma unroll
            for (int mi = 0; mi < 2; mi++)
#pragma unroll
                for (int ni = 0; ni < 2; ni++)
                    s[mi][ni] = __builtin_amdgcn_mfma_f32_16x16x32_bf16(ka[mi], qa[ni][d2], s[mi][ni], 0, 0, 0);
        }

        // exp2 (Q pre-scaled), pack 4 consecutive k -> wave-private Ps
#pragma unroll
        for (int ni = 0; ni < 2; ni++)
#pragma unroll
            for (int mi = 0; mi < 2; mi++) {
                float e0 = __builtin_amdgcn_exp2f(s[mi][ni][0]);
                float e1 = __builtin_amdgcn_exp2f(s[mi][ni][1]);
                float e2 = __builtin_amdgcn_exp2f(s[mi][ni][2]);
                float e3 = __builtin_amdgcn_exp2f(s[mi][ni][3]);
                u32x2 pk; pk.x = pk2(e0, e1); pk.y = pk2(e2, e3);
                *(u32x2*)&Pw[(ni * 16 + l16) * 40 + mi * 16 + quad * 4] = pk;
            }

        // O[q][d] += P[q][k32] V[k32][d]; l(q) += P*ones; same-wave LDS RAW
        {
            bf16x8 pa[2], vb[4];
#pragma unroll
            for (int ni = 0; ni < 2; ni++)
                pa[ni] = *(const bf16x8*)&Pw[(ni * 16 + l16) * 40 + quad * 8];
#pragma unroll
            for (int di = 0; di < 4; di++)
                vb[di] = *(const bf16x8*)&buf[vbase + 512 * di];
#pragma unroll
            for (int ni = 0; ni < 2; ni++) {
                acc_l[ni] = __builtin_amdgcn_mfma_f32_16x16x32_bf16(pa[ni], ones, acc_l[ni], 0, 0, 0);
#pragma unroll
                for (int di = 0; di < 4; di++)
                    acc_o[ni][di] = __builtin_amdgcn_mfma_f32_16x16x32_bf16(pa[ni], vb[di], acc_o[ni][di], 0, 0, 0);
            }
        }
        __syncthreads();
    }

    // normalize + store (coalesced along d = di*16 + l16)
#pragma unroll
    for (int ni = 0; ni < 2; ni++) {
#pragma unroll
        for (int r = 0; r < 4; r++) {
            float inv = __builtin_amdgcn_rcpf(acc_l[ni][r]);
            int row = w * 32 + ni * 16 + quad * 4 + r;
#pragma unroll
            for (int di = 0; di < 4; di++)
                Op[(size_t)row * 1024 + di * 16 + l16] = cvt1(acc_o[ni][di][r] * inv);
        }
    }
}

extern "C" void kernel_launch(void* const* d_in, const int* in_sizes, int n_in,
                              void* d_out, int out_size, void* d_ws, size_t ws_size,
                              hipStream_t stream)
{
    (void)in_sizes; (void)n_in; (void)out_size; (void)ws_size;
    // inputs (fp32): 0:x 4:Wq 5:bq 6:Wk 7:bk 8:Wv 9:bv 10:Wo 11:bo
    // 1,2,3,12..19: conditioning — mathematically cancels in softmax.
    const float* xf  = (const float*)d_in[0];
    const float* Wqf = (const float*)d_in[4];  const float* bqf = (const float*)d_in[5];
    const float* Wkf = (const float*)d_in[6];  const float* bkf = (const float*)d_in[7];
    const float* Wvf = (const float*)d_in[8];  const float* bvf = (const float*)d_in[9];
    const float* Wof = (const float*)d_in[10]; const float* bof = (const float*)d_in[11];

    u16* ws  = (u16*)d_ws;
    u16* Qw  = ws;                              // 8M el bf16 (pre-scaled by log2e/8)
    u16* Kw  = ws + (size_t)8388608;            // 8M el bf16
    u16* Vtw = ws + (size_t)16777216;           // 8M el bf16 [b*16+h][64][1024]
    u16* WT  = ws + (size_t)25165824;           // 4M el bf16 [4][n=1024][k=1024]
    u16* xb  = ws + (size_t)29360128;           // 8M el bf16 x; reused as AO after k_qkv
    u16* AO  = xb;

    k_prep<<<9216, 256, 0, stream>>>(xf, xb, Wqf, Wkf, Wvf, Wof, WT);
    k_qkvf<<<dim3(16, 64), 256, 0, stream>>>(xb, WT, bqf, bkf, bvf, Qw, Vtw);
    k_attn<<<dim3(128, 8), 256, 0, stream>>>(Qw, Kw, Vtw, AO);
    k_out4<<<dim3(8, 64), 256, 0, stream>>>(AO, WT + (size_t)3145728, bof, (float*)d_out);
}